// Round 9
// baseline (269.188 us; speedup 1.0000x reference)
//
#include <hip/hip_runtime.h>
#include <hip/hip_fp8.h>
#include <cstdint>
#include <cstddef>

#define N_NODES 50000
#define E_EDGES 800000
#define IN_F    128
#define PCOLS   512   // Pb cols: [0,96) Y0 | [96,192) Zpre | [192,288) Zblk | [288,480) Zpost | pad

typedef unsigned short ushortT;
typedef unsigned int   uintT;
typedef unsigned char  u8T;
typedef __attribute__((ext_vector_type(8))) short s8v;   // 8 bf16 (4 VGPR)
typedef __attribute__((ext_vector_type(4))) float f4v;   // 4 fp32 acc
typedef __attribute__((ext_vector_type(2))) float f2v;   // packed fp32 pair

__device__ __forceinline__ float bflo(uintT u){ union{uintT i;float f;}c; c.i=u<<16; return c.f; }
__device__ __forceinline__ float bfhi(uintT u){ union{uintT i;float f;}c; c.i=u&0xFFFF0000u; return c.f; }
__device__ __forceinline__ ushortT f2bfu(float f){
    union{float f;uintT u;}c; c.f=f;
    uintT r = c.u + 0x7FFF + ((c.u>>16)&1);
    return (ushortT)(r>>16);
}
__device__ __forceinline__ uintT pack2(float a, float b){
    return (uintT)f2bfu(a) | ((uintT)f2bfu(b) << 16);
}
// fp8 e4m3 (OCP on gfx950) helpers
__device__ __forceinline__ float f8f(uintT b){
    __hip_fp8_e4m3 h; h.__x = (__hip_fp8_storage_t)(b & 0xFF); return (float)h;
}
__device__ __forceinline__ uintT ff8(float f){
    __hip_fp8_e4m3 h(f); return (uintT)h.__x;
}
// packed fp8x2 -> f32x2 decode (HW v_cvt_pk_f32_fp8 on gfx940+), exact fallback
__device__ __forceinline__ f2v cvtpk_sw(uintT u, bool hi){
    uintT w = hi ? (u >> 16) : u;
    f2v r; r.x = f8f(w); r.y = f8f(w >> 8); return r;
}
#if defined(__has_builtin)
#if __has_builtin(__builtin_amdgcn_cvt_pk_f32_fp8)
#define CVTPK(u, hi) __builtin_amdgcn_cvt_pk_f32_fp8((u), (hi))
#else
#define CVTPK(u, hi) cvtpk_sw((u), (hi))
#endif
#else
#define CVTPK(u, hi) cvtpk_sw((u), (hi))
#endif

// ---------- prep1: pack weights + convert data + row_ptr + fp8 dummy rows ----------
// grid = 800000 threads exactly (N*IN_F/8)
__global__ void prep1(const float* __restrict__ A,
                      const float* __restrict__ Wp,  const float* __restrict__ bp,
                      const float* __restrict__ Tp,  const float* __restrict__ bTp,
                      const float* __restrict__ Tb,  const float* __restrict__ bTb,
                      const float* __restrict__ Tpo, const float* __restrict__ bTpo,
                      const float* __restrict__ Wpost,
                      const int* __restrict__ tgt,
                      ushortT* __restrict__ Wb, float* __restrict__ bcat,
                      float2* __restrict__ Wp2,
                      ushortT* __restrict__ Ab, int* __restrict__ row_ptr,
                      u8T* __restrict__ rb1f8, u8T* __restrict__ rb2f8)
{
    int gid = blockIdx.x * 256 + threadIdx.x;
    {
        size_t off = (size_t)gid * 8;
        float4 v0 = *(const float4*)(A + off);
        float4 v1 = *(const float4*)(A + off + 4);
        uint4 u;
        u.x = pack2(v0.x, v0.y); u.y = pack2(v0.z, v0.w);
        u.z = pack2(v1.x, v1.y); u.w = pack2(v1.z, v1.w);
        *(uint4*)(Ab + off) = u;
    }
    if (gid < IN_F * PCOLS) {
        int k = gid >> 9;
        int c = gid & 511;
        float v;
        if      (c < 96)  v = Wp [k*96  + c];
        else if (c < 192) v = Tp [k*96  + (c-96)];
        else if (c < 288) v = Tb [k*96  + (c-192)];
        else if (c < 480) v = Tpo[k*192 + (c-288)];
        else              v = 0.f;
        Wb[(size_t)c*IN_F + k] = f2bfu(v);
        if (k == 0) {
            float b;
            if      (c < 96)  b = bp  [c];
            else if (c < 192) b = bTp [c-96];
            else if (c < 288) b = bTb [c-192];
            else if (c < 480) b = bTpo[c-288];
            else              b = 0.f;
            bcat[c] = b;
        }
        if (gid < 3*16*64) {   // Wp2[(w*16+i2)*64+j] = (Wpost[w][2i2][j], Wpost[w][2i2+1][j])
            int w = gid >> 10, r = gid & 1023;
            int i2 = r >> 6, j = r & 63;
            Wp2[gid] = make_float2(Wpost[(w*32 + 2*i2)*64 + j],
                                   Wpost[(w*32 + 2*i2 + 1)*64 + j]);
        }
    }
    if (gid < 24) {   // fp8 dummy gather row (node N) = 0
        *(uintT*)(rb1f8 + (size_t)N_NODES*96 + 4*gid) = 0;
        *(uintT*)(rb2f8 + (size_t)N_NODES*96 + 4*gid) = 0;
    }
    if (gid <= N_NODES) {
        int lo = 0, hi = E_EDGES;
        while (lo < hi) {
            int mid = (lo + hi) >> 1;
            if (tgt[mid] < gid) lo = mid + 1; else hi = mid;
        }
        row_ptr[gid] = lo;
    }
}

// ---------- MFMA GEMM: Pb[M,512] = bf16(Ab[M,128] @ Wb^T + bcat) ----------
__global__ __launch_bounds__(256, 4) void gemm_mfma(const ushortT* __restrict__ Ab,
                                                    const ushortT* __restrict__ Wb,
                                                    const float* __restrict__ bcat,
                                                    ushortT* __restrict__ Pb, int M)
{
    __shared__ ushortT Bsl[128][136];   // 34816 B; B tile [n][k], reused as C staging
    int tid = threadIdx.x;
    int i = blockIdx.x;                  // 1568 = 8 * 49 * 4
    int xcd = i & 7, j = i >> 3;         // j in [0,196)
    int nb = (j & 3) * 128;              // column block
    int mb = (xcd * 49 + (j >> 2)) * 128;// row band (tail bands OOB-guarded)
    int wv = tid >> 6, lane = tid & 63;
    int wm = wv >> 1, wn = wv & 1;
    int cl = lane & 15, q = lane >> 4;

    #pragma unroll
    for (int r = 0; r < 8; ++r) {
        int idx = tid + 256*r;
        int row = idx >> 4, qq = idx & 15;
        uint4 v = *(const uint4*)(Wb + (size_t)(nb+row)*IN_F + qq*8);
        *(uint4*)(&Bsl[row][qq*8]) = v;
    }
    __syncthreads();

    f4v acc[4][4];
    #pragma unroll
    for (int a = 0; a < 4; ++a)
        #pragma unroll
        for (int b = 0; b < 4; ++b) acc[a][b] = (f4v)0.f;

    int gmBase = mb + wm*64;
    #pragma unroll
    for (int ks = 0; ks < 4; ++ks) {
        int ko = ks*32 + q*8;
        s8v af[4], bf[4];
        #pragma unroll
        for (int mt = 0; mt < 4; ++mt) {
            int gm = gmBase + mt*16 + cl;
            uint4 va = make_uint4(0,0,0,0);
            if (gm < M) va = *(const uint4*)(Ab + (size_t)gm*IN_F + ko);
            af[mt] = *(s8v*)&va;
        }
        #pragma unroll
        for (int nt = 0; nt < 4; ++nt)
            bf[nt] = *(const s8v*)(&Bsl[wn*64 + nt*16 + cl][ko]);
        #pragma unroll
        for (int mt = 0; mt < 4; ++mt)
            #pragma unroll
            for (int nt = 0; nt < 4; ++nt)
                acc[mt][nt] = __builtin_amdgcn_mfma_f32_16x16x32_bf16(af[mt], bf[nt], acc[mt][nt], 0, 0, 0);
    }

    __syncthreads();   // all waves done reading Bsl -> reuse as C staging

    #pragma unroll
    for (int nt = 0; nt < 4; ++nt) {
        int cn = wn*64 + nt*16 + cl;
        float bv = bcat[nb + cn];
        #pragma unroll
        for (int mt = 0; mt < 4; ++mt) {
            int rm0 = wm*64 + mt*16 + q*4;
            #pragma unroll
            for (int r = 0; r < 4; ++r)
                Bsl[rm0 + r][cn] = f2bfu(acc[mt][nt][r] + bv);
        }
    }
    __syncthreads();

    #pragma unroll
    for (int p = 0; p < 8; ++p) {
        int idx = tid + 256*p;
        int row = idx >> 4, sg = idx & 15;
        int gm = mb + row;
        if (gm < M) {
            uint4 v = *(const uint4*)(&Bsl[row][sg*8]);
            *(uint4*)(Pb + (size_t)gm*PCOLS + nb + sg*8) = v;
        }
    }
}

// ---------- cvt_y0: Y8[t][0..95] = fp8(Pb[t][0..95]) + zero dummy row ----------
__global__ void cvt_y0(const ushortT* __restrict__ Pb, u8T* __restrict__ Y8)
{
    int gid = blockIdx.x * 256 + threadIdx.x;
    if (gid < N_NODES*24) {
        int t = gid / 24, q = gid - t*24;
        uint2 rv = *(const uint2*)(Pb + (size_t)t*PCOLS + 4*q);
        uintT o = ff8(bflo(rv.x)) | (ff8(bfhi(rv.x)) << 8)
                | (ff8(bflo(rv.y)) << 16) | (ff8(bfhi(rv.y)) << 24);
        *(uintT*)(Y8 + (size_t)t*96 + 4*q) = o;
    } else if (gid < N_NODES*24 + 24) {
        *(uintT*)(Y8 + (size_t)N_NODES*96 + 4*(gid - N_NODES*24)) = 0;
    }
}

// ===== paired-edge fp8 gather =====
// fp8 row = 96 B = 24 uint lanes. Slot s: lanes 0-23 load 4 feats of edge 2s,
// lanes 24-47 edge 2s+1 (lanes 48-63 mirror 0-15, discarded). One load instr = 2 edges.
// Address: per-slot ds_bpermute pulls the row byte-offset from sv.
// After accumulation: parity-combine (lane <-> lane±24) + redistribute to 48x2 layout.
#define LANE_GEO8                                                                 \
    int lane = threadIdx.x & 63;                                                  \
    int pL = lane < 48 ? lane : 0;                                                \
    int lq = (lane < 24) ? lane : ((lane < 48) ? lane - 24 : lane - 48);          \
    int bpb = (lane >= 24 && lane < 48) ? 4 : 0;  /* bpermute byte base */        \
    int in4 = 4*lq;                               /* byte offset within row */

#define GPK_W(X8, sv, S0, CNT, u)                                                 \
    _Pragma("unroll")                                                             \
    for (int s_ = 0; s_ < (CNT); ++s_) {                                          \
        int vr_ = __builtin_amdgcn_ds_bpermute(bpb + 8*((S0)+s_), sv);            \
        u[s_] = *(const uintT*)((const u8T*)(X8) + (uintT)(vr_ + in4));           \
    }
#define GPK_D(u, CNT, a0, a1, b0, b1)                                             \
    _Pragma("unroll")                                                             \
    for (int s_ = 0; s_ < (CNT); ++s_) {                                          \
        f2v l_ = CVTPK(u[s_], 0);                                                 \
        f2v h_ = CVTPK(u[s_], 1);                                                 \
        if (s_ & 1) { b0 += l_; b1 += h_; } else { a0 += l_; a1 += h_; }          \
    }
// sx,sy = neighbor sum at feats (2*pL, 2*pL+1), valid for lane<48
#define GATHER_PK(X8, lo, deg, sv, sx, sy)                                        \
    float sx, sy;                                                                 \
    {                                                                             \
        f2v a0={0.f,0.f}, a1={0.f,0.f}, b0={0.f,0.f}, b1={0.f,0.f};               \
        uintT u[12];                                                              \
        GPK_W(X8, sv, 0, 12, u)                                                   \
        GPK_D(u, 12, a0, a1, b0, b1)                                              \
        if (deg > 24) {                                                           \
            GPK_W(X8, sv, 12, 12, u)                                              \
            GPK_D(u, 12, a0, a1, b0, b1)                                          \
        }                                                                         \
        if (deg > 48) {                                                           \
            GPK_W(X8, sv, 24, 8, u)                                               \
            GPK_D(u, 8, a0, a1, b0, b1)                                           \
        }                                                                         \
        if (deg > 64) {                                                           \
            _Pragma("unroll 1")                                                   \
            for (int j_ = lo + 64; j_ < lo + deg; ++j_) {                         \
                int off_ = src[j_] * 96;                                          \
                uintT t_ = *(const uintT*)((const u8T*)(X8) + (uintT)(off_ + in4));\
                if (lane < 24) { a0 += CVTPK(t_, 0); a1 += CVTPK(t_, 1); }        \
            }                                                                     \
        }                                                                         \
        f2v va = a0 + b0, vb = a1 + b1;   /* feats 4lq..4lq+3, this parity */     \
        /* FIX(r8): partner is lane±24, NOT lane^24 (XOR wrong for lanes 8-23) */ \
        int pl_ = (lane < 24) ? lane + 24 : ((lane < 48) ? lane - 24 : lane);     \
        va.x += __shfl(va.x, pl_); va.y += __shfl(va.y, pl_);                     \
        vb.x += __shfl(vb.x, pl_); vb.y += __shfl(vb.y, pl_);                     \
        int fl_ = pL >> 1;                                                        \
        float e0_ = __shfl(va.x, fl_), e1_ = __shfl(va.y, fl_);                   \
        float e2_ = __shfl(vb.x, fl_), e3_ = __shfl(vb.y, fl_);                   \
        sx = (pL & 1) ? e2_ : e0_;                                                \
        sy = (pL & 1) ? e3_ : e1_;                                                \
    }

// batched per-wave descriptors for 4 nodes (t0, t0+4, t0+8, t0+12):
// all row_ptr loads issue together, then all src loads -> 2 round trips per 4 nodes
#define DESC4(t0)                                                                 \
    int lo0,dg0,sv0, lo1,dg1,sv1, lo2,dg2,sv2, lo3,dg3,sv3;                       \
    {                                                                             \
        int rA0 = row_ptr[(t0)];    int rB0 = row_ptr[(t0)+1];                    \
        int rA1 = row_ptr[(t0)+4];  int rB1 = row_ptr[(t0)+5];                    \
        int rA2 = row_ptr[(t0)+8];  int rB2 = row_ptr[(t0)+9];                    \
        int rA3 = row_ptr[(t0)+12]; int rB3 = row_ptr[(t0)+13];                   \
        lo0 = __builtin_amdgcn_readfirstlane(rA0);                                \
        dg0 = __builtin_amdgcn_readfirstlane(rB0) - lo0;                          \
        lo1 = __builtin_amdgcn_readfirstlane(rA1);                                \
        dg1 = __builtin_amdgcn_readfirstlane(rB1) - lo1;                          \
        lo2 = __builtin_amdgcn_readfirstlane(rA2);                                \
        dg2 = __builtin_amdgcn_readfirstlane(rB2) - lo2;                          \
        lo3 = __builtin_amdgcn_readfirstlane(rA3);                                \
        dg3 = __builtin_amdgcn_readfirstlane(rB3) - lo3;                          \
        int e0 = lo0 + lane; if (e0 > E_EDGES-1) e0 = E_EDGES-1;                  \
        int e1 = lo1 + lane; if (e1 > E_EDGES-1) e1 = E_EDGES-1;                  \
        int e2 = lo2 + lane; if (e2 > E_EDGES-1) e2 = E_EDGES-1;                  \
        int e3 = lo3 + lane; if (e3 > E_EDGES-1) e3 = E_EDGES-1;                  \
        int sn0 = src[e0]; int sn1 = src[e1];                                     \
        int sn2 = src[e2]; int sn3 = src[e3];                                     \
        sv0 = (lane < dg0 ? sn0 : N_NODES) * 96;                                  \
        sv1 = (lane < dg1 ? sn1 : N_NODES) * 96;                                  \
        sv2 = (lane < dg2 ? sn2 : N_NODES) * 96;                                  \
        sv3 = (lane < dg3 ? sn3 : N_NODES) * 96;                                  \
    }

// ---------- layer 1: rb1 = bf16(relu(Lap(Y0) + Zpre)); persistent 4 nodes/wave ----------
__global__ __launch_bounds__(256) void lap1(
    const ushortT* __restrict__ Pb,    // own-x (cols 0..95) + Zpre (96..191), bf16
    const u8T*     __restrict__ Y8,    // fp8 gather source [N+1,96]
    const int* __restrict__ src, const int* __restrict__ row_ptr,
    ushortT* __restrict__ rb1, u8T* __restrict__ rb1f8)
{
    LANE_GEO8
    int wvw = threadIdx.x >> 6;
    int t0 = blockIdx.x*16 + wvw;
    DESC4(t0)

#define LAP1_IT(tt, lo, deg, sv)                                                  \
    {                                                                             \
        int t_ = __builtin_amdgcn_readfirstlane(tt);                              \
        uintT ux = *(const uintT*)(Pb + (size_t)t_*PCOLS + 2*pL);                 \
        uintT zu = *(const uintT*)(Pb + (size_t)t_*PCOLS + 96 + 2*pL);            \
        GATHER_PK(Y8, lo, deg, sv, sx, sy)                                        \
        float inv = (deg) > 0 ? 1.f/(float)(deg) : 0.f;                           \
        float mf  = (deg) > 0 ? 1.f : 0.f;                                        \
        if (lane < 48) {                                                          \
            float ox = fmaxf(mf*bflo(ux) - sx*inv + bflo(zu), 0.f);               \
            float oy = fmaxf(mf*bfhi(ux) - sy*inv + bfhi(zu), 0.f);               \
            *(uintT*)(rb1 + (size_t)t_*96 + 2*pL) = pack2(ox, oy);                \
            *(ushortT*)(rb1f8 + (size_t)t_*96 + 2*pL) =                           \
                (ushortT)(ff8(ox) | (ff8(oy) << 8));                              \
        }                                                                         \
    }
    LAP1_IT(t0,      lo0, dg0, sv0)
    LAP1_IT(t0 + 4,  lo1, dg1, sv1)
    LAP1_IT(t0 + 8,  lo2, dg2, sv2)
    LAP1_IT(t0 + 12, lo3, dg3, sv3)
#undef LAP1_IT
}

// ---------- layer 2: rb2 = bf16(relu(Lap(rb1)@W_blk + Zblk)); persistent ----------
__global__ __launch_bounds__(256) void lap2(
    const ushortT* __restrict__ Xb,    // rb1 bf16 (own-x)
    const u8T*     __restrict__ X8,    // rb1 fp8 (gather)
    const ushortT* __restrict__ Pb,    // Zblk = cols 192..287
    const int* __restrict__ src, const int* __restrict__ row_ptr,
    const float* __restrict__ Wblk,    // [3][32][32] flat
    ushortT* __restrict__ rb2, u8T* __restrict__ rb2f8)
{
    __shared__ float wS[3*32*32];
    for (int i = threadIdx.x; i < 3072; i += 256) wS[i] = Wblk[i];
    __syncthreads();

    LANE_GEO8
    int wvw = threadIdx.x >> 6;
    int w  = pL >> 4;            // group (uniform per 16-lane slab)
    int jj = pL & 15;            // out pair index within group
    const float2* wc = ((const float2*)wS) + (w*512 + jj);   // &W[w][0][2jj]
    int t0 = blockIdx.x*16 + wvw;
    DESC4(t0)

#define LAP2_IT(tt, lo, deg, sv)                                                  \
    {                                                                             \
        int t_ = __builtin_amdgcn_readfirstlane(tt);                              \
        uintT ux = *(const uintT*)(Xb + (size_t)t_*96 + 2*pL);                    \
        uintT zu = *(const uintT*)(Pb + (size_t)t_*PCOLS + 192 + 2*pL);           \
        GATHER_PK(X8, lo, deg, sv, sx, sy)                                        \
        float inv = (deg) > 0 ? 1.f/(float)(deg) : 0.f;                           \
        float mf  = (deg) > 0 ? 1.f : 0.f;                                        \
        float Lx = mf*bflo(ux) - sx*inv;                                          \
        float Ly = mf*bfhi(ux) - sy*inv;                                          \
        float accx = 0.f, accy = 0.f;                                             \
        _Pragma("unroll")                                                         \
        for (int d = 0; d < 16; ++d) {                                            \
            int sl = w*16 + d;                                                    \
            float ax = __shfl(Lx, sl);                                            \
            float ay = __shfl(Ly, sl);                                            \
            float2 wa = wc[(2*d)*16];                                             \
            float2 wb = wc[(2*d+1)*16];                                           \
            accx = fmaf(ax, wa.x, accx); accx = fmaf(ay, wb.x, accx);             \
            accy = fmaf(ax, wa.y, accy); accy = fmaf(ay, wb.y, accy);             \
        }                                                                         \
        if (lane < 48) {                                                          \
            float ox = fmaxf(accx + bflo(zu), 0.f);                               \
            float oy = fmaxf(accy + bfhi(zu), 0.f);                               \
            *(uintT*)(rb2 + (size_t)t_*96 + 2*pL) = pack2(ox, oy);                \
            *(ushortT*)(rb2f8 + (size_t)t_*96 + 2*pL) =                           \
                (ushortT)(ff8(ox) | (ff8(oy) << 8));                              \
        }                                                                         \
    }
    LAP2_IT(t0,      lo0, dg0, sv0)
    LAP2_IT(t0 + 4,  lo1, dg1, sv1)
    LAP2_IT(t0 + 8,  lo2, dg2, sv2)
    LAP2_IT(t0 + 12, lo3, dg3, sv3)
#undef LAP2_IT
}

// ---------- layer 3: out = widthmean(relu(Lap(rb2)@W_post + Zpost)); persistent ----------
__global__ __launch_bounds__(256) void lap3(
    const ushortT* __restrict__ Xb,    // rb2 bf16 (own-x)
    const u8T*     __restrict__ X8,    // rb2 fp8 (gather)
    const ushortT* __restrict__ Pb,    // Zpost = cols 288..479
    const int* __restrict__ src, const int* __restrict__ row_ptr,
    const float2* __restrict__ Wp2,    // [3][16][64] float2
    float* __restrict__ out)
{
    __shared__ float2 wS[3*16*64];
    __shared__ float  sm[4][96];       // per-wave activation slab (wave DS in-order)
    for (int i = threadIdx.x; i < 3072; i += 256) wS[i] = Wp2[i];
    __syncthreads();

    LANE_GEO8
    int wvw = threadIdx.x >> 6;
    const float2* wl = wS + lane;      // step 64 float2 per (w,i2)
    int t0 = blockIdx.x*16 + wvw;
    DESC4(t0)

#define LAP3_IT(tt, lo, deg, sv)                                                  \
    {                                                                             \
        int t_ = __builtin_amdgcn_readfirstlane(tt);                              \
        uintT ux = *(const uintT*)(Xb + (size_t)t_*96 + 2*pL);                    \
        float z0 = bflo((uintT)Pb[(size_t)t_*PCOLS + 288 + lane]);                \
        float z1 = bflo((uintT)Pb[(size_t)t_*PCOLS + 352 + lane]);                \
        float z2 = bflo((uintT)Pb[(size_t)t_*PCOLS + 416 + lane]);                \
        GATHER_PK(X8, lo, deg, sv, sx, sy)                                        \
        float inv = (deg) > 0 ? 1.f/(float)(deg) : 0.f;                           \
        float mf  = (deg) > 0 ? 1.f : 0.f;                                        \
        float Lx = mf*bflo(ux) - sx*inv;                                          \
        float Ly = mf*bfhi(ux) - sy*inv;                                          \
        if (lane < 48) {                                                          \
            sm[wvw][2*pL]     = Lx;                                               \
            sm[wvw][2*pL + 1] = Ly;                                               \
        }                                                                         \
        __builtin_amdgcn_wave_barrier();                                          \
        float a0 = 0.f, a1 = 0.f, a2 = 0.f;                                       \
        _Pragma("unroll")                                                         \
        for (int w2 = 0; w2 < 3; ++w2) {                                          \
            float acc = 0.f;                                                      \
            _Pragma("unroll")                                                     \
            for (int i2 = 0; i2 < 16; ++i2) {                                     \
                float2 iv = *(const float2*)(&sm[wvw][w2*32 + 2*i2]);             \
                float2 p  = wl[(w2*16 + i2)*64];                                  \
                acc = fmaf(iv.x, p.x, acc);                                       \
                acc = fmaf(iv.y, p.y, acc);                                       \
            }                                                                     \
            if (w2 == 0) a0 = acc; else if (w2 == 1) a1 = acc; else a2 = acc;     \
        }                                                                         \
        __builtin_amdgcn_wave_barrier();                                          \
        float o0 = fmaxf(a0 + z0, 0.f);                                           \
        float o1 = fmaxf(a1 + z1, 0.f);                                           \
        float o2 = fmaxf(a2 + z2, 0.f);                                           \
        float r = 0.f;                                                            \
        _Pragma("unroll")                                                         \
        for (int q = 0; q < 3; ++q) {                                             \
            int c = 3*lane + q;                                                   \
            int sl = c & 63, wsel = c >> 6;                                       \
            float v0 = __shfl(o0, sl);                                            \
            float v1 = __shfl(o1, sl);                                            \
            float v2 = __shfl(o2, sl);                                            \
            r += (wsel == 0) ? v0 : ((wsel == 1) ? v1 : v2);                      \
        }                                                                         \
        out[(size_t)t_*64 + lane] = r * (1.0f/3.0f);                              \
    }
    LAP3_IT(t0,      lo0, dg0, sv0)
    LAP3_IT(t0 + 4,  lo1, dg1, sv1)
    LAP3_IT(t0 + 8,  lo2, dg2, sv2)
    LAP3_IT(t0 + 12, lo3, dg3, sv3)
#undef LAP3_IT
}

extern "C" void kernel_launch(void* const* d_in, const int* in_sizes, int n_in,
                              void* d_out, int out_size, void* d_ws, size_t ws_size,
                              hipStream_t stream)
{
    const float* data    = (const float*)d_in[0];
    const int*   src     = (const int*)  d_in[1];
    const int*   tgt     = (const int*)  d_in[2];
    const float* W_pre   = (const float*)d_in[3];
    const float* b_pre   = (const float*)d_in[4];
    const float* T_pre   = (const float*)d_in[5];
    const float* bT_pre  = (const float*)d_in[6];
    const float* W_blk   = (const float*)d_in[7];
    const float* b_blk   = (const float*)d_in[8];   // cancels under Lap — unused
    const float* T_blk   = (const float*)d_in[9];
    const float* bT_blk  = (const float*)d_in[10];
    const float* W_post  = (const float*)d_in[11];
    const float* b_post  = (const float*)d_in[12];  // cancels under Lap — unused
    const float* T_post  = (const float*)d_in[13];
    const float* bT_post = (const float*)d_in[14];
    float* out = (float*)d_out;

    float*   ws      = (float*)d_ws;
    float*   bcat    = ws;                                   // 512 f32
    float2*  Wp2     = (float2*)(bcat + 512);                // 3*16*64 float2
    int*     row_ptr = (int*)(Wp2 + 3*16*64);                // 50008
    ushortT* Pb      = (ushortT*)(row_ptr + 50008);          // (N+1)*512 bf16
    ushortT* rb1     = Pb  + (size_t)(N_NODES+1) * PCOLS;    // (N+1)*96 bf16
    ushortT* rb2     = rb1 + (size_t)(N_NODES+1) * 96;       // (N+1)*96 bf16
    ushortT* Ab      = rb2 + (size_t)(N_NODES+1) * 96;       // N*128 bf16
    ushortT* Wb      = Ab  + (size_t)N_NODES * IN_F;         // 512*128 bf16
    u8T*     Y8      = (u8T*)(Wb + 512*IN_F);                // (N+1)*96 fp8
    u8T*     rb1f8   = Y8  + (size_t)(N_NODES+1) * 96;       // (N+1)*96 fp8
    u8T*     rb2f8   = rb1f8 + (size_t)(N_NODES+1) * 96;     // (N+1)*96 fp8

    prep1<<<(N_NODES*IN_F/8)/256, 256, 0, stream>>>(
        data, W_pre, b_pre, T_pre, bT_pre, T_blk, bT_blk, T_post, bT_post,
        W_post, tgt, Wb, bcat, Wp2, Ab, row_ptr, rb1f8, rb2f8);

    gemm_mfma<<<1568, 256, 0, stream>>>(Ab, Wb, bcat, Pb, N_NODES);

    cvt_y0<<<(N_NODES*24 + 24 + 255)/256, 256, 0, stream>>>(Pb, Y8);

    lap1<<<N_NODES/16, 256, 0, stream>>>(Pb, Y8, src, row_ptr, rb1, rb1f8);
    lap2<<<N_NODES/16, 256, 0, stream>>>(rb1, rb1f8, Pb, src, row_ptr, W_blk, rb2, rb2f8);
    lap3<<<N_NODES/16, 256, 0, stream>>>(rb2, rb2f8, Pb, src, row_ptr, Wp2, out);
}

// Round 10
// 265.237 us; speedup vs baseline: 1.0149x; 1.0149x over previous
//
#include <hip/hip_runtime.h>
#include <hip/hip_fp8.h>
#include <cstdint>
#include <cstddef>

#define N_NODES 50000
#define E_EDGES 800000
#define IN_F    128
#define PCOLS   512   // Pb cols: [0,96) Y0 | [96,192) Zpre | [192,288) Zblk | [288,480) Zpost | pad

typedef unsigned short ushortT;
typedef unsigned int   uintT;
typedef unsigned char  u8T;
typedef __attribute__((ext_vector_type(8))) short s8v;   // 8 bf16 (4 VGPR)
typedef __attribute__((ext_vector_type(4))) float f4v;   // 4 fp32 acc
typedef __attribute__((ext_vector_type(2))) float f2v;   // packed fp32 pair

__device__ __forceinline__ float bflo(uintT u){ union{uintT i;float f;}c; c.i=u<<16; return c.f; }
__device__ __forceinline__ float bfhi(uintT u){ union{uintT i;float f;}c; c.i=u&0xFFFF0000u; return c.f; }
__device__ __forceinline__ ushortT f2bfu(float f){
    union{float f;uintT u;}c; c.f=f;
    uintT r = c.u + 0x7FFF + ((c.u>>16)&1);
    return (ushortT)(r>>16);
}
__device__ __forceinline__ uintT pack2(float a, float b){
    return (uintT)f2bfu(a) | ((uintT)f2bfu(b) << 16);
}
// fp8 e4m3 (OCP on gfx950) helpers
__device__ __forceinline__ float f8f(uintT b){
    __hip_fp8_e4m3 h; h.__x = (__hip_fp8_storage_t)(b & 0xFF); return (float)h;
}
__device__ __forceinline__ uintT ff8(float f){
    __hip_fp8_e4m3 h(f); return (uintT)h.__x;
}
// packed fp8x2 -> f32x2 decode (HW v_cvt_pk_f32_fp8), exact fallback
__device__ __forceinline__ f2v cvtpk_sw(uintT u, bool hi){
    uintT w = hi ? (u >> 16) : u;
    f2v r; r.x = f8f(w); r.y = f8f(w >> 8); return r;
}
#if defined(__has_builtin)
#if __has_builtin(__builtin_amdgcn_cvt_pk_f32_fp8)
#define CVTPK(u, hi) __builtin_amdgcn_cvt_pk_f32_fp8((u), (hi))
#else
#define CVTPK(u, hi) cvtpk_sw((u), (hi))
#endif
#else
#define CVTPK(u, hi) cvtpk_sw((u), (hi))
#endif

// ---------- prep1: pack weights + convert data + row_ptr + fp8 dummy rows ----------
// grid = 800000 threads exactly (N*IN_F/8)
__global__ void prep1(const float* __restrict__ A,
                      const float* __restrict__ Wp,  const float* __restrict__ bp,
                      const float* __restrict__ Tp,  const float* __restrict__ bTp,
                      const float* __restrict__ Tb,  const float* __restrict__ bTb,
                      const float* __restrict__ Tpo, const float* __restrict__ bTpo,
                      const float* __restrict__ Wpost,
                      const int* __restrict__ tgt,
                      ushortT* __restrict__ Wb, float* __restrict__ bcat,
                      float2* __restrict__ Wp2,
                      ushortT* __restrict__ Ab, int* __restrict__ row_ptr,
                      u8T* __restrict__ rb1f8, u8T* __restrict__ rb2f8)
{
    int gid = blockIdx.x * 256 + threadIdx.x;
    {
        size_t off = (size_t)gid * 8;
        float4 v0 = *(const float4*)(A + off);
        float4 v1 = *(const float4*)(A + off + 4);
        uint4 u;
        u.x = pack2(v0.x, v0.y); u.y = pack2(v0.z, v0.w);
        u.z = pack2(v1.x, v1.y); u.w = pack2(v1.z, v1.w);
        *(uint4*)(Ab + off) = u;
    }
    if (gid < IN_F * PCOLS) {
        int k = gid >> 9;
        int c = gid & 511;
        float v;
        if      (c < 96)  v = Wp [k*96  + c];
        else if (c < 192) v = Tp [k*96  + (c-96)];
        else if (c < 288) v = Tb [k*96  + (c-192)];
        else if (c < 480) v = Tpo[k*192 + (c-288)];
        else              v = 0.f;
        Wb[(size_t)c*IN_F + k] = f2bfu(v);
        if (k == 0) {
            float b;
            if      (c < 96)  b = bp  [c];
            else if (c < 192) b = bTp [c-96];
            else if (c < 288) b = bTb [c-192];
            else if (c < 480) b = bTpo[c-288];
            else              b = 0.f;
            bcat[c] = b;
        }
        if (gid < 3*16*64) {   // Wp2[(w*16+i2)*64+j] = (Wpost[w][2i2][j], Wpost[w][2i2+1][j])
            int w = gid >> 10, r = gid & 1023;
            int i2 = r >> 6, j = r & 63;
            Wp2[gid] = make_float2(Wpost[(w*32 + 2*i2)*64 + j],
                                   Wpost[(w*32 + 2*i2 + 1)*64 + j]);
        }
    }
    if (gid < 24) {   // fp8 dummy gather row (node N) = 0
        *(uintT*)(rb1f8 + (size_t)N_NODES*96 + 4*gid) = 0;
        *(uintT*)(rb2f8 + (size_t)N_NODES*96 + 4*gid) = 0;
    }
    if (gid <= N_NODES) {
        int lo = 0, hi = E_EDGES;
        while (lo < hi) {
            int mid = (lo + hi) >> 1;
            if (tgt[mid] < gid) lo = mid + 1; else hi = mid;
        }
        row_ptr[gid] = lo;
    }
}

// ---------- build_svp: svp[t*64+slot] = (slot<deg ? src[lo+slot] : N) * 96 ----------
// pre-scaled fp8-row byte offsets; deletes the per-node row_ptr->src serial chain
// from every lap. grid = N*64/256 threads.
__global__ void build_svp(const int* __restrict__ src, const int* __restrict__ row_ptr,
                          int* __restrict__ svp)
{
    int gid = blockIdx.x * 256 + threadIdx.x;
    int t = gid >> 6, slot = gid & 63;
    int lo = row_ptr[t];
    int deg = row_ptr[t+1] - lo;
    int e = lo + slot; if (e > E_EDGES - 1) e = E_EDGES - 1;
    int v = slot < deg ? src[e] : N_NODES;
    svp[gid] = v * 96;
}

// ---------- MFMA GEMM: Pb[M,512] = bf16(Ab[M,128] @ Wb^T + bcat) ----------
__global__ __launch_bounds__(256, 4) void gemm_mfma(const ushortT* __restrict__ Ab,
                                                    const ushortT* __restrict__ Wb,
                                                    const float* __restrict__ bcat,
                                                    ushortT* __restrict__ Pb, int M)
{
    __shared__ ushortT Bsl[128][136];   // 34816 B; B tile [n][k], reused as C staging
    int tid = threadIdx.x;
    int i = blockIdx.x;                  // 1568 = 8 * 49 * 4
    int xcd = i & 7, j = i >> 3;         // j in [0,196)
    int nb = (j & 3) * 128;              // column block
    int mb = (xcd * 49 + (j >> 2)) * 128;// row band (tail bands OOB-guarded)
    int wv = tid >> 6, lane = tid & 63;
    int wm = wv >> 1, wn = wv & 1;
    int cl = lane & 15, q = lane >> 4;

    #pragma unroll
    for (int r = 0; r < 8; ++r) {
        int idx = tid + 256*r;
        int row = idx >> 4, qq = idx & 15;
        uint4 v = *(const uint4*)(Wb + (size_t)(nb+row)*IN_F + qq*8);
        *(uint4*)(&Bsl[row][qq*8]) = v;
    }
    __syncthreads();

    f4v acc[4][4];
    #pragma unroll
    for (int a = 0; a < 4; ++a)
        #pragma unroll
        for (int b = 0; b < 4; ++b) acc[a][b] = (f4v)0.f;

    int gmBase = mb + wm*64;
    #pragma unroll
    for (int ks = 0; ks < 4; ++ks) {
        int ko = ks*32 + q*8;
        s8v af[4], bf[4];
        #pragma unroll
        for (int mt = 0; mt < 4; ++mt) {
            int gm = gmBase + mt*16 + cl;
            uint4 va = make_uint4(0,0,0,0);
            if (gm < M) va = *(const uint4*)(Ab + (size_t)gm*IN_F + ko);
            af[mt] = *(s8v*)&va;
        }
        #pragma unroll
        for (int nt = 0; nt < 4; ++nt)
            bf[nt] = *(const s8v*)(&Bsl[wn*64 + nt*16 + cl][ko]);
        #pragma unroll
        for (int mt = 0; mt < 4; ++mt)
            #pragma unroll
            for (int nt = 0; nt < 4; ++nt)
                acc[mt][nt] = __builtin_amdgcn_mfma_f32_16x16x32_bf16(af[mt], bf[nt], acc[mt][nt], 0, 0, 0);
    }

    __syncthreads();   // all waves done reading Bsl -> reuse as C staging

    #pragma unroll
    for (int nt = 0; nt < 4; ++nt) {
        int cn = wn*64 + nt*16 + cl;
        float bv = bcat[nb + cn];
        #pragma unroll
        for (int mt = 0; mt < 4; ++mt) {
            int rm0 = wm*64 + mt*16 + q*4;
            #pragma unroll
            for (int r = 0; r < 4; ++r)
                Bsl[rm0 + r][cn] = f2bfu(acc[mt][nt][r] + bv);
        }
    }
    __syncthreads();

    #pragma unroll
    for (int p = 0; p < 8; ++p) {
        int idx = tid + 256*p;
        int row = idx >> 4, sg = idx & 15;
        int gm = mb + row;
        if (gm < M) {
            uint4 v = *(const uint4*)(&Bsl[row][sg*8]);
            *(uint4*)(Pb + (size_t)gm*PCOLS + nb + sg*8) = v;
        }
    }
}

// ---------- cvt_y0: Y8[t][0..95] = fp8(Pb[t][0..95]) + zero dummy row ----------
__global__ void cvt_y0(const ushortT* __restrict__ Pb, u8T* __restrict__ Y8)
{
    int gid = blockIdx.x * 256 + threadIdx.x;
    if (gid < N_NODES*24) {
        int t = gid / 24, q = gid - t*24;
        uint2 rv = *(const uint2*)(Pb + (size_t)t*PCOLS + 4*q);
        uintT o = ff8(bflo(rv.x)) | (ff8(bfhi(rv.x)) << 8)
                | (ff8(bflo(rv.y)) << 16) | (ff8(bfhi(rv.y)) << 24);
        *(uintT*)(Y8 + (size_t)t*96 + 4*q) = o;
    } else if (gid < N_NODES*24 + 24) {
        *(uintT*)(Y8 + (size_t)N_NODES*96 + 4*(gid - N_NODES*24)) = 0;
    }
}

// ===== gather core (fp8 source): 16-deep windows; rows 96 B, 2B/lane loads =====
// sv = PRE-SCALED byte offset (row*96) loaded from svp (no per-node src chain).
// Lane loads ushort (2 fp8 feats) at row + 2*pL; packed HW decode via CVTPK.
#define GATHER96F8(X8, lo, deg, sv, pL, sx, sy)                                   \
    float sx, sy;                                                                 \
    {                                                                             \
        f2v c0={0.f,0.f}, c1={0.f,0.f}, c2={0.f,0.f}, c3={0.f,0.f};               \
        int dmax = deg < 64 ? deg : 64;                                           \
        _Pragma("unroll 1")                                                       \
        for (int w_ = 0; w_ < dmax; w_ += 16) {                                   \
            uintT u[16];                                                          \
            _Pragma("unroll")                                                     \
            for (int kk = 0; kk < 16; ++kk) {                                     \
                int off = __builtin_amdgcn_readlane(sv, w_ + kk);                 \
                u[kk] = *(const ushortT*)((const u8T*)(X8) + off + 2*pL);         \
            }                                                                     \
            _Pragma("unroll")                                                     \
            for (int kk = 0; kk < 16; ++kk) {                                     \
                f2v v_ = CVTPK(u[kk], 0);                                         \
                switch (kk & 3) {                                                 \
                    case 0: c0 += v_; break;                                      \
                    case 1: c1 += v_; break;                                      \
                    case 2: c2 += v_; break;                                      \
                    default:c3 += v_; break;                                      \
                }                                                                 \
            }                                                                     \
        }                                                                         \
        if (deg > 64) {                                                           \
            _Pragma("unroll 1")                                                   \
            for (int j_ = lo + 64; j_ < lo + deg; ++j_) {                         \
                int off = src[j_] * 96;                                           \
                uintT u0 = *(const ushortT*)((const u8T*)(X8) + off + 2*pL);      \
                c0 += CVTPK(u0, 0);                                               \
            }                                                                     \
        }                                                                         \
        f2v cs_ = (c0 + c1) + (c2 + c3);                                          \
        sx = cs_.x; sy = cs_.y;                                                   \
    }

// upfront per-wave state for 4 nodes tB, tB+4, tB+8, tB+12:
// issue all 4 coalesced svp loads + all row_ptr descriptor loads in parallel.
#define DESC_SVP(tB)                                                              \
    int sv0 = svp[(size_t)((tB)     )*64 + lane];                                 \
    int sv1 = svp[(size_t)((tB) +  4)*64 + lane];                                 \
    int sv2 = svp[(size_t)((tB) +  8)*64 + lane];                                 \
    int sv3 = svp[(size_t)((tB) + 12)*64 + lane];                                 \
    int rA0 = row_ptr[(tB)];    int rB0 = row_ptr[(tB)+1];                        \
    int rA1 = row_ptr[(tB)+4];  int rB1 = row_ptr[(tB)+5];                        \
    int rA2 = row_ptr[(tB)+8];  int rB2 = row_ptr[(tB)+9];                        \
    int rA3 = row_ptr[(tB)+12]; int rB3 = row_ptr[(tB)+13];                       \
    int lo0 = __builtin_amdgcn_readfirstlane(rA0);                                \
    int dg0 = __builtin_amdgcn_readfirstlane(rB0) - lo0;                          \
    int lo1 = __builtin_amdgcn_readfirstlane(rA1);                                \
    int dg1 = __builtin_amdgcn_readfirstlane(rB1) - lo1;                          \
    int lo2 = __builtin_amdgcn_readfirstlane(rA2);                                \
    int dg2 = __builtin_amdgcn_readfirstlane(rB2) - lo2;                          \
    int lo3 = __builtin_amdgcn_readfirstlane(rA3);                                \
    int dg3 = __builtin_amdgcn_readfirstlane(rB3) - lo3;

// ---------- layer 1: rb1 = bf16(relu(Lap(Y0) + Zpre)); 4 nodes/wave ----------
__global__ __launch_bounds__(256) void lap1(
    const ushortT* __restrict__ Pb,    // own-x (cols 0..95) + Zpre (96..191), bf16
    const u8T*     __restrict__ Y8,    // fp8 gather source [N+1,96]
    const int* __restrict__ src, const int* __restrict__ row_ptr,
    const int* __restrict__ svp,
    ushortT* __restrict__ rb1, u8T* __restrict__ rb1f8)
{
    int lane = threadIdx.x & 63;
    int wvw  = threadIdx.x >> 6;
    int pL = lane < 48 ? lane : 0;
    int tB = blockIdx.x*16 + wvw;
    DESC_SVP(tB)

#define LAP1_IT(tt, lo, deg, sv)                                                  \
    {                                                                             \
        int t_ = __builtin_amdgcn_readfirstlane(tt);                              \
        uintT ux = *(const uintT*)(Pb + (size_t)t_*PCOLS + 2*pL);                 \
        uintT zu = *(const uintT*)(Pb + (size_t)t_*PCOLS + 96 + 2*pL);            \
        GATHER96F8(Y8, lo, deg, sv, pL, sx, sy)                                   \
        float inv = (deg) > 0 ? 1.f/(float)(deg) : 0.f;                           \
        float mf  = (deg) > 0 ? 1.f : 0.f;                                        \
        if (lane < 48) {                                                          \
            float ox = fmaxf(mf*bflo(ux) - sx*inv + bflo(zu), 0.f);               \
            float oy = fmaxf(mf*bfhi(ux) - sy*inv + bfhi(zu), 0.f);               \
            *(uintT*)(rb1 + (size_t)t_*96 + 2*pL) = pack2(ox, oy);                \
            *(ushortT*)(rb1f8 + (size_t)t_*96 + 2*pL) =                           \
                (ushortT)(ff8(ox) | (ff8(oy) << 8));                              \
        }                                                                         \
    }
    LAP1_IT(tB,      lo0, dg0, sv0)
    LAP1_IT(tB + 4,  lo1, dg1, sv1)
    LAP1_IT(tB + 8,  lo2, dg2, sv2)
    LAP1_IT(tB + 12, lo3, dg3, sv3)
#undef LAP1_IT
}

// ---------- layer 2: rb2 = bf16(relu(Lap(rb1)@W_blk + Zblk)); 4 nodes/wave ----------
__global__ __launch_bounds__(256) void lap2(
    const ushortT* __restrict__ Xb,    // rb1 bf16 (own-x)
    const u8T*     __restrict__ X8,    // rb1 fp8 (gather)
    const ushortT* __restrict__ Pb,    // Zblk = cols 192..287
    const int* __restrict__ src, const int* __restrict__ row_ptr,
    const int* __restrict__ svp,
    const float* __restrict__ Wblk,    // [3][32][32] flat
    ushortT* __restrict__ rb2, u8T* __restrict__ rb2f8)
{
    __shared__ float wS[3*32*32];
    int lane = threadIdx.x & 63;
    int wvw  = threadIdx.x >> 6;
    int pL = lane < 48 ? lane : 0;
    int tB = blockIdx.x*16 + wvw;
    DESC_SVP(tB)                 // loads in flight during weight staging + barrier

    for (int i = threadIdx.x; i < 3072; i += 256) wS[i] = Wblk[i];
    __syncthreads();

    int w  = pL >> 4;            // group (uniform per 16-lane slab)
    int jj = pL & 15;            // out pair index within group
    const float2* wc = ((const float2*)wS) + (w*512 + jj);   // &W[w][0][2jj]

#define LAP2_IT(tt, lo, deg, sv)                                                  \
    {                                                                             \
        int t_ = __builtin_amdgcn_readfirstlane(tt);                              \
        uintT ux = *(const uintT*)(Xb + (size_t)t_*96 + 2*pL);                    \
        uintT zu = *(const uintT*)(Pb + (size_t)t_*PCOLS + 192 + 2*pL);           \
        GATHER96F8(X8, lo, deg, sv, pL, sx, sy)                                   \
        float inv = (deg) > 0 ? 1.f/(float)(deg) : 0.f;                           \
        float mf  = (deg) > 0 ? 1.f : 0.f;                                        \
        float Lx = mf*bflo(ux) - sx*inv;                                          \
        float Ly = mf*bfhi(ux) - sy*inv;                                          \
        float accx = 0.f, accy = 0.f;                                             \
        _Pragma("unroll")                                                         \
        for (int d = 0; d < 16; ++d) {                                            \
            int sl = w*16 + d;                                                    \
            float ax = __shfl(Lx, sl);                                            \
            float ay = __shfl(Ly, sl);                                            \
            float2 wa = wc[(2*d)*16];                                             \
            float2 wb = wc[(2*d+1)*16];                                           \
            accx = fmaf(ax, wa.x, accx); accx = fmaf(ay, wb.x, accx);             \
            accy = fmaf(ax, wa.y, accy); accy = fmaf(ay, wb.y, accy);             \
        }                                                                         \
        if (lane < 48) {                                                          \
            float ox = fmaxf(accx + bflo(zu), 0.f);                               \
            float oy = fmaxf(accy + bfhi(zu), 0.f);                               \
            *(uintT*)(rb2 + (size_t)t_*96 + 2*pL) = pack2(ox, oy);                \
            *(ushortT*)(rb2f8 + (size_t)t_*96 + 2*pL) =                           \
                (ushortT)(ff8(ox) | (ff8(oy) << 8));                              \
        }                                                                         \
    }
    LAP2_IT(tB,      lo0, dg0, sv0)
    LAP2_IT(tB + 4,  lo1, dg1, sv1)
    LAP2_IT(tB + 8,  lo2, dg2, sv2)
    LAP2_IT(tB + 12, lo3, dg3, sv3)
#undef LAP2_IT
}

// ---------- layer 3: out = widthmean(relu(Lap(rb2)@W_post + Zpost)); 4 nodes/wave ----------
__global__ __launch_bounds__(256) void lap3(
    const ushortT* __restrict__ Xb,    // rb2 bf16 (own-x)
    const u8T*     __restrict__ X8,    // rb2 fp8 (gather)
    const ushortT* __restrict__ Pb,    // Zpost = cols 288..479
    const int* __restrict__ src, const int* __restrict__ row_ptr,
    const int* __restrict__ svp,
    const float2* __restrict__ Wp2,    // [3][16][64] float2
    float* __restrict__ out)
{
    __shared__ float2 wS[3*16*64];
    __shared__ float  sm[4][96];       // per-wave activation slab (wave DS in-order)
    int lane = threadIdx.x & 63;
    int wvw  = threadIdx.x >> 6;
    int pL = lane < 48 ? lane : 0;
    int tB = blockIdx.x*16 + wvw;
    DESC_SVP(tB)                 // loads in flight during weight staging + barrier

    for (int i = threadIdx.x; i < 3072; i += 256) wS[i] = Wp2[i];
    __syncthreads();

    const float2* wl = wS + lane;      // step 64 float2 per (w,i2)

#define LAP3_IT(tt, lo, deg, sv)                                                  \
    {                                                                             \
        int t_ = __builtin_amdgcn_readfirstlane(tt);                              \
        uintT ux = *(const uintT*)(Xb + (size_t)t_*96 + 2*pL);                    \
        float z0 = bflo((uintT)Pb[(size_t)t_*PCOLS + 288 + lane]);                \
        float z1 = bflo((uintT)Pb[(size_t)t_*PCOLS + 352 + lane]);                \
        float z2 = bflo((uintT)Pb[(size_t)t_*PCOLS + 416 + lane]);                \
        GATHER96F8(X8, lo, deg, sv, pL, sx, sy)                                   \
        float inv = (deg) > 0 ? 1.f/(float)(deg) : 0.f;                           \
        float mf  = (deg) > 0 ? 1.f : 0.f;                                        \
        float Lx = mf*bflo(ux) - sx*inv;                                          \
        float Ly = mf*bfhi(ux) - sy*inv;                                          \
        if (lane < 48) {                                                          \
            sm[wvw][2*pL]     = Lx;                                               \
            sm[wvw][2*pL + 1] = Ly;                                               \
        }                                                                         \
        __builtin_amdgcn_wave_barrier();                                          \
        float a0 = 0.f, a1 = 0.f, a2 = 0.f;                                       \
        _Pragma("unroll")                                                         \
        for (int w2 = 0; w2 < 3; ++w2) {                                          \
            float acc = 0.f;                                                      \
            _Pragma("unroll")                                                     \
            for (int i2 = 0; i2 < 16; ++i2) {                                     \
                float2 iv = *(const float2*)(&sm[wvw][w2*32 + 2*i2]);             \
                float2 p  = wl[(w2*16 + i2)*64];                                  \
                acc = fmaf(iv.x, p.x, acc);                                       \
                acc = fmaf(iv.y, p.y, acc);                                       \
            }                                                                     \
            if (w2 == 0) a0 = acc; else if (w2 == 1) a1 = acc; else a2 = acc;     \
        }                                                                         \
        __builtin_amdgcn_wave_barrier();                                          \
        float o0 = fmaxf(a0 + z0, 0.f);                                           \
        float o1 = fmaxf(a1 + z1, 0.f);                                           \
        float o2 = fmaxf(a2 + z2, 0.f);                                           \
        float r = 0.f;                                                            \
        _Pragma("unroll")                                                         \
        for (int q = 0; q < 3; ++q) {                                             \
            int c = 3*lane + q;                                                   \
            int sl = c & 63, wsel = c >> 6;                                       \
            float v0 = __shfl(o0, sl);                                            \
            float v1 = __shfl(o1, sl);                                            \
            float v2 = __shfl(o2, sl);                                            \
            r += (wsel == 0) ? v0 : ((wsel == 1) ? v1 : v2);                      \
        }                                                                         \
        out[(size_t)t_*64 + lane] = r * (1.0f/3.0f);                              \
    }
    LAP3_IT(tB,      lo0, dg0, sv0)
    LAP3_IT(tB + 4,  lo1, dg1, sv1)
    LAP3_IT(tB + 8,  lo2, dg2, sv2)
    LAP3_IT(tB + 12, lo3, dg3, sv3)
#undef LAP3_IT
}

extern "C" void kernel_launch(void* const* d_in, const int* in_sizes, int n_in,
                              void* d_out, int out_size, void* d_ws, size_t ws_size,
                              hipStream_t stream)
{
    const float* data    = (const float*)d_in[0];
    const int*   src     = (const int*)  d_in[1];
    const int*   tgt     = (const int*)  d_in[2];
    const float* W_pre   = (const float*)d_in[3];
    const float* b_pre   = (const float*)d_in[4];
    const float* T_pre   = (const float*)d_in[5];
    const float* bT_pre  = (const float*)d_in[6];
    const float* W_blk   = (const float*)d_in[7];
    const float* b_blk   = (const float*)d_in[8];   // cancels under Lap — unused
    const float* T_blk   = (const float*)d_in[9];
    const float* bT_blk  = (const float*)d_in[10];
    const float* W_post  = (const float*)d_in[11];
    const float* b_post  = (const float*)d_in[12];  // cancels under Lap — unused
    const float* T_post  = (const float*)d_in[13];
    const float* bT_post = (const float*)d_in[14];
    float* out = (float*)d_out;

    float*   ws      = (float*)d_ws;
    float*   bcat    = ws;                                   // 512 f32
    float2*  Wp2     = (float2*)(bcat + 512);                // 3*16*64 float2
    int*     row_ptr = (int*)(Wp2 + 3*16*64);                // 50008
    ushortT* Pb      = (ushortT*)(row_ptr + 50008);          // (N+1)*512 bf16
    ushortT* rb1     = Pb  + (size_t)(N_NODES+1) * PCOLS;    // (N+1)*96 bf16
    ushortT* rb2     = rb1 + (size_t)(N_NODES+1) * 96;       // (N+1)*96 bf16
    ushortT* Ab      = rb2 + (size_t)(N_NODES+1) * 96;       // N*128 bf16
    ushortT* Wb      = Ab  + (size_t)N_NODES * IN_F;         // 512*128 bf16
    u8T*     Y8      = (u8T*)(Wb + 512*IN_F);                // (N+1)*96 fp8
    u8T*     rb1f8   = Y8  + (size_t)(N_NODES+1) * 96;       // (N+1)*96 fp8
    u8T*     rb2f8   = rb1f8 + (size_t)(N_NODES+1) * 96;     // (N+1)*96 fp8
    int*     svp     = (int*)(rb2f8 + (size_t)(N_NODES+1) * 96 + 32); // N*64 int (aligned)
    svp = (int*)(((uintptr_t)svp + 15) & ~(uintptr_t)15);

    prep1<<<(N_NODES*IN_F/8)/256, 256, 0, stream>>>(
        data, W_pre, b_pre, T_pre, bT_pre, T_blk, bT_blk, T_post, bT_post,
        W_post, tgt, Wb, bcat, Wp2, Ab, row_ptr, rb1f8, rb2f8);

    build_svp<<<(N_NODES*64)/256, 256, 0, stream>>>(src, row_ptr, svp);

    gemm_mfma<<<1568, 256, 0, stream>>>(Ab, Wb, bcat, Pb, N_NODES);

    cvt_y0<<<(N_NODES*24 + 24 + 255)/256, 256, 0, stream>>>(Pb, Y8);

    lap1<<<N_NODES/16, 256, 0, stream>>>(Pb, Y8, src, row_ptr, svp, rb1, rb1f8);
    lap2<<<N_NODES/16, 256, 0, stream>>>(rb1, rb1f8, Pb, src, row_ptr, svp, W_blk, rb2, rb2f8);
    lap3<<<N_NODES/16, 256, 0, stream>>>(rb2, rb2f8, Pb, src, row_ptr, svp, Wp2, out);
}

// Round 11
// 258.105 us; speedup vs baseline: 1.0429x; 1.0276x over previous
//
#include <hip/hip_runtime.h>
#include <hip/hip_fp8.h>
#include <cstdint>
#include <cstddef>

#define N_NODES 50000
#define E_EDGES 800000
#define IN_F    128
#define PCOLS   512   // Pb cols: [0,96) Y0 | [96,192) Zpre | [192,288) Zblk | [288,480) Zpost | pad

typedef unsigned short ushortT;
typedef unsigned int   uintT;
typedef unsigned char  u8T;
typedef __attribute__((ext_vector_type(8))) short s8v;   // 8 bf16 (4 VGPR)
typedef __attribute__((ext_vector_type(4))) float f4v;   // 4 fp32 acc
typedef __attribute__((ext_vector_type(2))) float f2v;   // packed fp32 pair

__device__ __forceinline__ float bflo(uintT u){ union{uintT i;float f;}c; c.i=u<<16; return c.f; }
__device__ __forceinline__ float bfhi(uintT u){ union{uintT i;float f;}c; c.i=u&0xFFFF0000u; return c.f; }
__device__ __forceinline__ ushortT f2bfu(float f){
    union{float f;uintT u;}c; c.f=f;
    uintT r = c.u + 0x7FFF + ((c.u>>16)&1);
    return (ushortT)(r>>16);
}
__device__ __forceinline__ uintT pack2(float a, float b){
    return (uintT)f2bfu(a) | ((uintT)f2bfu(b) << 16);
}
// fp8 e4m3 (OCP on gfx950) helpers
__device__ __forceinline__ float f8f(uintT b){
    __hip_fp8_e4m3 h; h.__x = (__hip_fp8_storage_t)(b & 0xFF); return (float)h;
}
__device__ __forceinline__ uintT ff8(float f){
    __hip_fp8_e4m3 h(f); return (uintT)h.__x;
}
// packed fp8x2 -> f32x2 decode (HW v_cvt_pk_f32_fp8), exact fallback.
// Proven correct + VALU-cheap in r10; here applied WITHOUT r10's descriptor
// batching (which caused the r10 regression via upfront load drain).
__device__ __forceinline__ f2v cvtpk_sw(uintT u, bool hi){
    uintT w = hi ? (u >> 16) : u;
    f2v r; r.x = f8f(w); r.y = f8f(w >> 8); return r;
}
#if defined(__has_builtin)
#if __has_builtin(__builtin_amdgcn_cvt_pk_f32_fp8)
#define CVTPK(u, hi) __builtin_amdgcn_cvt_pk_f32_fp8((u), (hi))
#else
#define CVTPK(u, hi) cvtpk_sw((u), (hi))
#endif
#else
#define CVTPK(u, hi) cvtpk_sw((u), (hi))
#endif

// ---------- prep1: pack weights + convert data + row_ptr + fp8 dummy rows ----------
// grid = 800000 threads exactly (N*IN_F/8)
__global__ void prep1(const float* __restrict__ A,
                      const float* __restrict__ Wp,  const float* __restrict__ bp,
                      const float* __restrict__ Tp,  const float* __restrict__ bTp,
                      const float* __restrict__ Tb,  const float* __restrict__ bTb,
                      const float* __restrict__ Tpo, const float* __restrict__ bTpo,
                      const float* __restrict__ Wpost,
                      const int* __restrict__ tgt,
                      ushortT* __restrict__ Wb, float* __restrict__ bcat,
                      float2* __restrict__ Wp2,
                      ushortT* __restrict__ Ab, int* __restrict__ row_ptr,
                      u8T* __restrict__ rb1f8, u8T* __restrict__ rb2f8)
{
    int gid = blockIdx.x * 256 + threadIdx.x;
    {
        size_t off = (size_t)gid * 8;
        float4 v0 = *(const float4*)(A + off);
        float4 v1 = *(const float4*)(A + off + 4);
        uint4 u;
        u.x = pack2(v0.x, v0.y); u.y = pack2(v0.z, v0.w);
        u.z = pack2(v1.x, v1.y); u.w = pack2(v1.z, v1.w);
        *(uint4*)(Ab + off) = u;
    }
    if (gid < IN_F * PCOLS) {
        int k = gid >> 9;
        int c = gid & 511;
        float v;
        if      (c < 96)  v = Wp [k*96  + c];
        else if (c < 192) v = Tp [k*96  + (c-96)];
        else if (c < 288) v = Tb [k*96  + (c-192)];
        else if (c < 480) v = Tpo[k*192 + (c-288)];
        else              v = 0.f;
        Wb[(size_t)c*IN_F + k] = f2bfu(v);
        if (k == 0) {
            float b;
            if      (c < 96)  b = bp  [c];
            else if (c < 192) b = bTp [c-96];
            else if (c < 288) b = bTb [c-192];
            else if (c < 480) b = bTpo[c-288];
            else              b = 0.f;
            bcat[c] = b;
        }
        if (gid < 3*16*64) {   // Wp2[(w*16+i2)*64+j] = (Wpost[w][2i2][j], Wpost[w][2i2+1][j])
            int w = gid >> 10, r = gid & 1023;
            int i2 = r >> 6, j = r & 63;
            Wp2[gid] = make_float2(Wpost[(w*32 + 2*i2)*64 + j],
                                   Wpost[(w*32 + 2*i2 + 1)*64 + j]);
        }
    }
    if (gid < 24) {   // fp8 dummy gather row (node N) = 0
        *(uintT*)(rb1f8 + (size_t)N_NODES*96 + 4*gid) = 0;
        *(uintT*)(rb2f8 + (size_t)N_NODES*96 + 4*gid) = 0;
    }
    if (gid <= N_NODES) {
        int lo = 0, hi = E_EDGES;
        while (lo < hi) {
            int mid = (lo + hi) >> 1;
            if (tgt[mid] < gid) lo = mid + 1; else hi = mid;
        }
        row_ptr[gid] = lo;
    }
}

// ---------- MFMA GEMM: Pb[M,512] = bf16(Ab[M,128] @ Wb^T + bcat) ----------
__global__ __launch_bounds__(256, 4) void gemm_mfma(const ushortT* __restrict__ Ab,
                                                    const ushortT* __restrict__ Wb,
                                                    const float* __restrict__ bcat,
                                                    ushortT* __restrict__ Pb, int M)
{
    __shared__ ushortT Bsl[128][136];   // 34816 B; B tile [n][k], reused as C staging
    int tid = threadIdx.x;
    int i = blockIdx.x;                  // 1568 = 8 * 49 * 4
    int xcd = i & 7, j = i >> 3;         // j in [0,196)
    int nb = (j & 3) * 128;              // column block
    int mb = (xcd * 49 + (j >> 2)) * 128;// row band (tail bands OOB-guarded)
    int wv = tid >> 6, lane = tid & 63;
    int wm = wv >> 1, wn = wv & 1;
    int cl = lane & 15, q = lane >> 4;

    #pragma unroll
    for (int r = 0; r < 8; ++r) {
        int idx = tid + 256*r;
        int row = idx >> 4, qq = idx & 15;
        uint4 v = *(const uint4*)(Wb + (size_t)(nb+row)*IN_F + qq*8);
        *(uint4*)(&Bsl[row][qq*8]) = v;
    }
    __syncthreads();

    f4v acc[4][4];
    #pragma unroll
    for (int a = 0; a < 4; ++a)
        #pragma unroll
        for (int b = 0; b < 4; ++b) acc[a][b] = (f4v)0.f;

    int gmBase = mb + wm*64;
    #pragma unroll
    for (int ks = 0; ks < 4; ++ks) {
        int ko = ks*32 + q*8;
        s8v af[4], bf[4];
        #pragma unroll
        for (int mt = 0; mt < 4; ++mt) {
            int gm = gmBase + mt*16 + cl;
            uint4 va = make_uint4(0,0,0,0);
            if (gm < M) va = *(const uint4*)(Ab + (size_t)gm*IN_F + ko);
            af[mt] = *(s8v*)&va;
        }
        #pragma unroll
        for (int nt = 0; nt < 4; ++nt)
            bf[nt] = *(const s8v*)(&Bsl[wn*64 + nt*16 + cl][ko]);
        #pragma unroll
        for (int mt = 0; mt < 4; ++mt)
            #pragma unroll
            for (int nt = 0; nt < 4; ++nt)
                acc[mt][nt] = __builtin_amdgcn_mfma_f32_16x16x32_bf16(af[mt], bf[nt], acc[mt][nt], 0, 0, 0);
    }

    __syncthreads();   // all waves done reading Bsl -> reuse as C staging

    #pragma unroll
    for (int nt = 0; nt < 4; ++nt) {
        int cn = wn*64 + nt*16 + cl;
        float bv = bcat[nb + cn];
        #pragma unroll
        for (int mt = 0; mt < 4; ++mt) {
            int rm0 = wm*64 + mt*16 + q*4;
            #pragma unroll
            for (int r = 0; r < 4; ++r)
                Bsl[rm0 + r][cn] = f2bfu(acc[mt][nt][r] + bv);
        }
    }
    __syncthreads();

    #pragma unroll
    for (int p = 0; p < 8; ++p) {
        int idx = tid + 256*p;
        int row = idx >> 4, sg = idx & 15;
        int gm = mb + row;
        if (gm < M) {
            uint4 v = *(const uint4*)(&Bsl[row][sg*8]);
            *(uint4*)(Pb + (size_t)gm*PCOLS + nb + sg*8) = v;
        }
    }
}

// ---------- cvt_y0: Y8[t][0..95] = fp8(Pb[t][0..95]) + zero dummy row ----------
__global__ void cvt_y0(const ushortT* __restrict__ Pb, u8T* __restrict__ Y8)
{
    int gid = blockIdx.x * 256 + threadIdx.x;
    if (gid < N_NODES*24) {
        int t = gid / 24, q = gid - t*24;
        uint2 rv = *(const uint2*)(Pb + (size_t)t*PCOLS + 4*q);
        uintT o = ff8(bflo(rv.x)) | (ff8(bfhi(rv.x)) << 8)
                | (ff8(bflo(rv.y)) << 16) | (ff8(bfhi(rv.y)) << 24);
        *(uintT*)(Y8 + (size_t)t*96 + 4*q) = o;
    } else if (gid < N_NODES*24 + 24) {
        *(uintT*)(Y8 + (size_t)N_NODES*96 + 4*(gid - N_NODES*24)) = 0;
    }
}

// ===== gather core (fp8 source): 16-deep windows; rows 96 B, 2B/lane loads =====
// sv holds PRE-SCALED byte offsets (row*96). Lane loads ushort (2 fp8 feats) at
// row + 2*pL; packed HW decode (1 v_cvt_pk_f32_fp8 per 2 feats — the only change
// vs the r6 best-known kernel).
#define GATHER96F8(X8, lo, deg, sv, pL, sx, sy)                                   \
    float sx, sy;                                                                 \
    {                                                                             \
        f2v c0={0.f,0.f}, c1={0.f,0.f}, c2={0.f,0.f}, c3={0.f,0.f};               \
        int dmax = deg < 64 ? deg : 64;                                           \
        _Pragma("unroll 1")                                                       \
        for (int w_ = 0; w_ < dmax; w_ += 16) {                                   \
            uintT u[16];                                                          \
            _Pragma("unroll")                                                     \
            for (int kk = 0; kk < 16; ++kk) {                                     \
                int off = __builtin_amdgcn_readlane(sv, w_ + kk);                 \
                u[kk] = *(const ushortT*)((const u8T*)(X8) + off + 2*pL);         \
            }                                                                     \
            _Pragma("unroll")                                                     \
            for (int kk = 0; kk < 16; ++kk) {                                     \
                f2v v_ = CVTPK(u[kk], 0);                                         \
                switch (kk & 3) {                                                 \
                    case 0: c0 += v_; break;                                      \
                    case 1: c1 += v_; break;                                      \
                    case 2: c2 += v_; break;                                      \
                    default:c3 += v_; break;                                      \
                }                                                                 \
            }                                                                     \
        }                                                                         \
        if (deg > 64) {                                                           \
            _Pragma("unroll 1")                                                   \
            for (int j_ = lo + 64; j_ < lo + deg; ++j_) {                         \
                int off = src[j_] * 96;                                           \
                uintT u0 = *(const ushortT*)((const u8T*)(X8) + off + 2*pL);      \
                c0 += CVTPK(u0, 0);                                               \
            }                                                                     \
        }                                                                         \
        f2v cs_ = (c0 + c1) + (c2 + c3);                                          \
        sx = cs_.x; sy = cs_.y;                                                   \
    }

// per-lane gather slot from raw src: lane<deg ? src[lo+lane]*96 : dummy row N
// (kept PER-ITERATION — r9/r10 proved upfront batching regresses via load drain)
#define MAKE_SV96(lo, deg, lane, sv)                                              \
    int sv;                                                                       \
    {                                                                             \
        int e_ = (lo) + (lane);                                                   \
        if (e_ > E_EDGES - 1) e_ = E_EDGES - 1;                                   \
        int sn_ = src[e_];                                                        \
        sv = ((lane) < (deg) ? sn_ : N_NODES) * 96;                               \
    }

// ---------- layer 1: rb1 = bf16(relu(Lap(Y0) + Zpre)); gather from fp8 Y8 ----------
__global__ __launch_bounds__(256) void lap1(
    const ushortT* __restrict__ Pb,    // own-x (cols 0..95) + Zpre (96..191), bf16
    const u8T*     __restrict__ Y8,    // fp8 gather source [N+1,96]
    const int* __restrict__ src, const int* __restrict__ row_ptr,
    ushortT* __restrict__ rb1, u8T* __restrict__ rb1f8)
{
    int lane = threadIdx.x & 63;
    int t  = __builtin_amdgcn_readfirstlane((blockIdx.x << 2) + (threadIdx.x >> 6));
    int lo = __builtin_amdgcn_readfirstlane(row_ptr[t]);
    int deg = __builtin_amdgcn_readfirstlane(row_ptr[t+1]) - lo;
    int pL = lane < 48 ? lane : 0;
    MAKE_SV96(lo, deg, lane, sv)
    uintT ux = *(const uintT*)(Pb + (size_t)t*PCOLS + 2*pL);        // Y0 bf16
    uintT zu = *(const uintT*)(Pb + (size_t)t*PCOLS + 96 + 2*pL);   // Zpre

    GATHER96F8(Y8, lo, deg, sv, pL, sx, sy)

    float inv = deg > 0 ? 1.f/(float)deg : 0.f;
    float mf  = deg > 0 ? 1.f : 0.f;
    if (lane < 48) {
        float ox = fmaxf(mf*bflo(ux) - sx*inv + bflo(zu), 0.f);
        float oy = fmaxf(mf*bfhi(ux) - sy*inv + bfhi(zu), 0.f);
        *(uintT*)(rb1 + (size_t)t*96 + 2*pL) = pack2(ox, oy);
        *(ushortT*)(rb1f8 + (size_t)t*96 + 2*pL) = (ushortT)(ff8(ox) | (ff8(oy) << 8));
    }
}

// ---------- layer 2: rb2 = bf16(relu(Lap(rb1)@W_blk + Zblk)); gather fp8 ----------
__global__ __launch_bounds__(256) void lap2(
    const ushortT* __restrict__ Xb,    // rb1 bf16 (own-x)
    const u8T*     __restrict__ X8,    // rb1 fp8 (gather)
    const ushortT* __restrict__ Pb,    // Zblk = cols 192..287
    const int* __restrict__ src, const int* __restrict__ row_ptr,
    const float* __restrict__ Wblk,    // [3][32][32] flat
    ushortT* __restrict__ rb2, u8T* __restrict__ rb2f8)
{
    __shared__ float wS[3*32*32];
    for (int i = threadIdx.x; i < 3072; i += 256) wS[i] = Wblk[i];
    __syncthreads();

    int lane = threadIdx.x & 63;
    int wvw  = threadIdx.x >> 6;
    int pL = lane < 48 ? lane : 0;
    int w  = pL >> 4;            // group (uniform per 16-lane slab)
    int jj = pL & 15;            // out pair index within group
    const float2* wc = ((const float2*)wS) + (w*512 + jj);   // &W[w][0][2jj]

    #pragma unroll 1
    for (int it = 0; it < 4; ++it) {
        int t  = __builtin_amdgcn_readfirstlane(blockIdx.x*16 + it*4 + wvw);
        int lo = __builtin_amdgcn_readfirstlane(row_ptr[t]);
        int deg = __builtin_amdgcn_readfirstlane(row_ptr[t+1]) - lo;
        MAKE_SV96(lo, deg, lane, sv)
        uintT ux = *(const uintT*)(Xb + (size_t)t*96 + 2*pL);
        uintT zu = *(const uintT*)(Pb + (size_t)t*PCOLS + 192 + 2*pL);

        GATHER96F8(X8, lo, deg, sv, pL, sx, sy)

        float inv = deg > 0 ? 1.f/(float)deg : 0.f;
        float mf  = deg > 0 ? 1.f : 0.f;
        float Lx = mf*bflo(ux) - sx*inv;    // Lap feat 2pL
        float Ly = mf*bfhi(ux) - sy*inv;    // Lap feat 2pL+1

        // conv (no bias): out channels (2pL, 2pL+1), inputs = group-w feats via shfl
        float accx = 0.f, accy = 0.f;
        #pragma unroll
        for (int d = 0; d < 16; ++d) {
            int sl = w*16 + d;
            float ax = __shfl(Lx, sl);      // feat 32w+2d
            float ay = __shfl(Ly, sl);      // feat 32w+2d+1
            float2 wa = wc[(2*d)*16];       // W[w][2d][2jj..2jj+1]
            float2 wb = wc[(2*d+1)*16];
            accx = fmaf(ax, wa.x, accx); accx = fmaf(ay, wb.x, accx);
            accy = fmaf(ax, wa.y, accy); accy = fmaf(ay, wb.y, accy);
        }
        if (lane < 48) {
            float ox = fmaxf(accx + bflo(zu), 0.f);
            float oy = fmaxf(accy + bfhi(zu), 0.f);
            *(uintT*)(rb2 + (size_t)t*96 + 2*pL) = pack2(ox, oy);
            *(ushortT*)(rb2f8 + (size_t)t*96 + 2*pL) = (ushortT)(ff8(ox) | (ff8(oy) << 8));
        }
    }
}

// ---------- layer 3: out = widthmean(relu(Lap(rb2)@W_post + Zpost)); gather fp8 ----------
__global__ __launch_bounds__(256) void lap3(
    const ushortT* __restrict__ Xb,    // rb2 bf16 (own-x)
    const u8T*     __restrict__ X8,    // rb2 fp8 (gather)
    const ushortT* __restrict__ Pb,    // Zpost = cols 288..479
    const int* __restrict__ src, const int* __restrict__ row_ptr,
    const float2* __restrict__ Wp2,    // [3][16][64] float2
    float* __restrict__ out)
{
    __shared__ float2 wS[3*16*64];
    __shared__ float  sm[4][96];       // per-wave activation slab (wave DS in-order)
    for (int i = threadIdx.x; i < 3072; i += 256) wS[i] = Wp2[i];
    __syncthreads();

    int lane = threadIdx.x & 63;
    int wvw  = threadIdx.x >> 6;
    int pL = lane < 48 ? lane : 0;
    const float2* wl = wS + lane;      // step 64 float2 per (w,i2)

    #pragma unroll 1
    for (int it = 0; it < 4; ++it) {
        int t  = __builtin_amdgcn_readfirstlane(blockIdx.x*16 + it*4 + wvw);
        int lo = __builtin_amdgcn_readfirstlane(row_ptr[t]);
        int deg = __builtin_amdgcn_readfirstlane(row_ptr[t+1]) - lo;
        MAKE_SV96(lo, deg, lane, sv)
        uintT ux = *(const uintT*)(Xb + (size_t)t*96 + 2*pL);
        float z0 = bflo((uintT)Pb[(size_t)t*PCOLS + 288 + lane]);   // ch lane
        float z1 = bflo((uintT)Pb[(size_t)t*PCOLS + 352 + lane]);   // ch 64+lane
        float z2 = bflo((uintT)Pb[(size_t)t*PCOLS + 416 + lane]);   // ch 128+lane

        GATHER96F8(X8, lo, deg, sv, pL, sx, sy)

        float inv = deg > 0 ? 1.f/(float)deg : 0.f;
        float mf  = deg > 0 ? 1.f : 0.f;
        float Lx = mf*bflo(ux) - sx*inv;
        float Ly = mf*bfhi(ux) - sy*inv;

        // broadcast activations through per-wave LDS (uniform-address ds_read = broadcast)
        if (lane < 48) {
            sm[wvw][2*pL]     = Lx;
            sm[wvw][2*pL + 1] = Ly;
        }
        __builtin_amdgcn_wave_barrier();   // pin compiler order; wave DS ops are HW-in-order

        // conv: lane computes channels {L, 64+L, 128+L}
        float a0 = 0.f, a1 = 0.f, a2 = 0.f;
        #pragma unroll
        for (int w2 = 0; w2 < 3; ++w2) {
            float acc = 0.f;
            #pragma unroll
            for (int i2 = 0; i2 < 16; ++i2) {
                float2 iv = *(const float2*)(&sm[wvw][w2*32 + 2*i2]);   // broadcast read
                float2 p  = wl[(w2*16 + i2)*64];
                acc = fmaf(iv.x, p.x, acc);
                acc = fmaf(iv.y, p.y, acc);
            }
            if (w2 == 0) a0 = acc; else if (w2 == 1) a1 = acc; else a2 = acc;
        }
        __builtin_amdgcn_wave_barrier();   // reads done before next iter's sm writes

        float o0 = fmaxf(a0 + z0, 0.f);   // channel lane
        float o1 = fmaxf(a1 + z1, 0.f);   // channel 64+lane
        float o2 = fmaxf(a2 + z2, 0.f);   // channel 128+lane
        // width-mean: final[f] = (v(3f)+v(3f+1)+v(3f+2))/3, v(c) = o_{c>>6} @ lane c&63
        float r = 0.f;
        #pragma unroll
        for (int q = 0; q < 3; ++q) {
            int c = 3*lane + q;
            int sl = c & 63, wsel = c >> 6;
            float v0 = __shfl(o0, sl);
            float v1 = __shfl(o1, sl);
            float v2 = __shfl(o2, sl);
            r += (wsel == 0) ? v0 : ((wsel == 1) ? v1 : v2);
        }
        out[(size_t)t*64 + lane] = r * (1.0f/3.0f);
    }
}

extern "C" void kernel_launch(void* const* d_in, const int* in_sizes, int n_in,
                              void* d_out, int out_size, void* d_ws, size_t ws_size,
                              hipStream_t stream)
{
    const float* data    = (const float*)d_in[0];
    const int*   src     = (const int*)  d_in[1];
    const int*   tgt     = (const int*)  d_in[2];
    const float* W_pre   = (const float*)d_in[3];
    const float* b_pre   = (const float*)d_in[4];
    const float* T_pre   = (const float*)d_in[5];
    const float* bT_pre  = (const float*)d_in[6];
    const float* W_blk   = (const float*)d_in[7];
    const float* b_blk   = (const float*)d_in[8];   // cancels under Lap — unused
    const float* T_blk   = (const float*)d_in[9];
    const float* bT_blk  = (const float*)d_in[10];
    const float* W_post  = (const float*)d_in[11];
    const float* b_post  = (const float*)d_in[12];  // cancels under Lap — unused
    const float* T_post  = (const float*)d_in[13];
    const float* bT_post = (const float*)d_in[14];
    float* out = (float*)d_out;

    float*   ws      = (float*)d_ws;
    float*   bcat    = ws;                                   // 512 f32
    float2*  Wp2     = (float2*)(bcat + 512);                // 3*16*64 float2
    int*     row_ptr = (int*)(Wp2 + 3*16*64);                // 50008
    ushortT* Pb      = (ushortT*)(row_ptr + 50008);          // (N+1)*512 bf16
    ushortT* rb1     = Pb  + (size_t)(N_NODES+1) * PCOLS;    // (N+1)*96 bf16
    ushortT* rb2     = rb1 + (size_t)(N_NODES+1) * 96;       // (N+1)*96 bf16
    ushortT* Ab      = rb2 + (size_t)(N_NODES+1) * 96;       // N*128 bf16
    ushortT* Wb      = Ab  + (size_t)N_NODES * IN_F;         // 512*128 bf16
    u8T*     Y8      = (u8T*)(Wb + 512*IN_F);                // (N+1)*96 fp8
    u8T*     rb1f8   = Y8  + (size_t)(N_NODES+1) * 96;       // (N+1)*96 fp8
    u8T*     rb2f8   = rb1f8 + (size_t)(N_NODES+1) * 96;     // (N+1)*96 fp8

    prep1<<<(N_NODES*IN_F/8)/256, 256, 0, stream>>>(
        data, W_pre, b_pre, T_pre, bT_pre, T_blk, bT_blk, T_post, bT_post,
        W_post, tgt, Wb, bcat, Wp2, Ab, row_ptr, rb1f8, rb2f8);

    gemm_mfma<<<1568, 256, 0, stream>>>(Ab, Wb, bcat, Pb, N_NODES);

    cvt_y0<<<(N_NODES*24 + 24 + 255)/256, 256, 0, stream>>>(Pb, Y8);

    lap1<<<N_NODES/4, 256, 0, stream>>>(Pb, Y8, src, row_ptr, rb1, rb1f8);
    lap2<<<N_NODES/16, 256, 0, stream>>>(rb1, rb1f8, Pb, src, row_ptr, W_blk, rb2, rb2f8);
    lap3<<<N_NODES/16, 256, 0, stream>>>(rb2, rb2f8, Pb, src, row_ptr, Wp2, out);
}

// Round 12
// 256.676 us; speedup vs baseline: 1.0487x; 1.0056x over previous
//
#include <hip/hip_runtime.h>
#include <hip/hip_fp8.h>
#include <cstdint>
#include <cstddef>

#define N_NODES 50000
#define E_EDGES 800000
#define IN_F    128
#define PCOLS   512   // Pb cols: [0,96) Y0 | [96,192) Zpre | [192,288) Zblk | [288,480) Zpost | pad

typedef unsigned short ushortT;
typedef unsigned int   uintT;
typedef unsigned char  u8T;
typedef __attribute__((ext_vector_type(8))) short s8v;   // 8 bf16 (4 VGPR)
typedef __attribute__((ext_vector_type(4))) float f4v;   // 4 fp32 acc
typedef __attribute__((ext_vector_type(2))) float f2v;   // packed fp32 pair

__device__ __forceinline__ float bflo(uintT u){ union{uintT i;float f;}c; c.i=u<<16; return c.f; }
__device__ __forceinline__ float bfhi(uintT u){ union{uintT i;float f;}c; c.i=u&0xFFFF0000u; return c.f; }
__device__ __forceinline__ ushortT f2bfu(float f){
    union{float f;uintT u;}c; c.f=f;
    uintT r = c.u + 0x7FFF + ((c.u>>16)&1);
    return (ushortT)(r>>16);
}
__device__ __forceinline__ uintT pack2(float a, float b){
    return (uintT)f2bfu(a) | ((uintT)f2bfu(b) << 16);
}
// fp8 e4m3 (OCP on gfx950) helpers
__device__ __forceinline__ float f8f(uintT b){
    __hip_fp8_e4m3 h; h.__x = (__hip_fp8_storage_t)(b & 0xFF); return (float)h;
}
__device__ __forceinline__ uintT ff8(float f){
    __hip_fp8_e4m3 h(f); return (uintT)h.__x;
}
// packed fp8x2 -> f32x2 decode (HW v_cvt_pk_f32_fp8), exact fallback
__device__ __forceinline__ f2v cvtpk_sw(uintT u, bool hi){
    uintT w = hi ? (u >> 16) : u;
    f2v r; r.x = f8f(w); r.y = f8f(w >> 8); return r;
}
#if defined(__has_builtin)
#if __has_builtin(__builtin_amdgcn_cvt_pk_f32_fp8)
#define CVTPK(u, hi) __builtin_amdgcn_cvt_pk_f32_fp8((u), (hi))
#else
#define CVTPK(u, hi) cvtpk_sw((u), (hi))
#endif
#else
#define CVTPK(u, hi) cvtpk_sw((u), (hi))
#endif

// ---------- prep1: pack weights + convert data + row_ptr + fp8 dummy rows ----------
// grid = 800000 threads exactly (N*IN_F/8)
__global__ void prep1(const float* __restrict__ A,
                      const float* __restrict__ Wp,  const float* __restrict__ bp,
                      const float* __restrict__ Tp,  const float* __restrict__ bTp,
                      const float* __restrict__ Tb,  const float* __restrict__ bTb,
                      const float* __restrict__ Tpo, const float* __restrict__ bTpo,
                      const float* __restrict__ Wpost,
                      const int* __restrict__ tgt,
                      ushortT* __restrict__ Wb, float* __restrict__ bcat,
                      float2* __restrict__ Wp2,
                      ushortT* __restrict__ Ab, int* __restrict__ row_ptr,
                      u8T* __restrict__ Y8,
                      u8T* __restrict__ rb1f8, u8T* __restrict__ rb2f8)
{
    int gid = blockIdx.x * 256 + threadIdx.x;
    {
        size_t off = (size_t)gid * 8;
        float4 v0 = *(const float4*)(A + off);
        float4 v1 = *(const float4*)(A + off + 4);
        uint4 u;
        u.x = pack2(v0.x, v0.y); u.y = pack2(v0.z, v0.w);
        u.z = pack2(v1.x, v1.y); u.w = pack2(v1.z, v1.w);
        *(uint4*)(Ab + off) = u;
    }
    if (gid < IN_F * PCOLS) {
        int k = gid >> 9;
        int c = gid & 511;
        float v;
        if      (c < 96)  v = Wp [k*96  + c];
        else if (c < 192) v = Tp [k*96  + (c-96)];
        else if (c < 288) v = Tb [k*96  + (c-192)];
        else if (c < 480) v = Tpo[k*192 + (c-288)];
        else              v = 0.f;
        Wb[(size_t)c*IN_F + k] = f2bfu(v);
        if (k == 0) {
            float b;
            if      (c < 96)  b = bp  [c];
            else if (c < 192) b = bTp [c-96];
            else if (c < 288) b = bTb [c-192];
            else if (c < 480) b = bTpo[c-288];
            else              b = 0.f;
            bcat[c] = b;
        }
        if (gid < 3*16*64) {   // Wp2[(w*16+i2)*64+j] = (Wpost[w][2i2][j], Wpost[w][2i2+1][j])
            int w = gid >> 10, r = gid & 1023;
            int i2 = r >> 6, j = r & 63;
            Wp2[gid] = make_float2(Wpost[(w*32 + 2*i2)*64 + j],
                                   Wpost[(w*32 + 2*i2 + 1)*64 + j]);
        }
    }
    if (gid < 24) {   // fp8 dummy gather row (node N) = 0 in all three gather sources
        *(uintT*)(Y8    + (size_t)N_NODES*96 + 4*gid) = 0;
        *(uintT*)(rb1f8 + (size_t)N_NODES*96 + 4*gid) = 0;
        *(uintT*)(rb2f8 + (size_t)N_NODES*96 + 4*gid) = 0;
    }
    if (gid <= N_NODES) {
        int lo = 0, hi = E_EDGES;
        while (lo < hi) {
            int mid = (lo + hi) >> 1;
            if (tgt[mid] < gid) lo = mid + 1; else hi = mid;
        }
        row_ptr[gid] = lo;
    }
}

// ---------- MFMA GEMM: Pb[M,512] = bf16(Ab[M,128] @ Wb^T + bcat) ----------
// nb==0 blocks additionally emit Y8 = fp8(C cols 0..95) straight from the LDS
// C staging (replaces the separate cvt_y0 kernel: -9.6MB read, -1 dispatch).
__global__ __launch_bounds__(256, 4) void gemm_mfma(const ushortT* __restrict__ Ab,
                                                    const ushortT* __restrict__ Wb,
                                                    const float* __restrict__ bcat,
                                                    ushortT* __restrict__ Pb,
                                                    u8T* __restrict__ Y8, int M)
{
    __shared__ ushortT Bsl[128][136];   // 34816 B; B tile [n][k], reused as C staging
    int tid = threadIdx.x;
    int i = blockIdx.x;                  // 1568 = 8 * 49 * 4
    int xcd = i & 7, j = i >> 3;         // j in [0,196)
    int nb = (j & 3) * 128;              // column block
    int mb = (xcd * 49 + (j >> 2)) * 128;// row band (tail bands OOB-guarded)
    int wv = tid >> 6, lane = tid & 63;
    int wm = wv >> 1, wn = wv & 1;
    int cl = lane & 15, q = lane >> 4;

    #pragma unroll
    for (int r = 0; r < 8; ++r) {
        int idx = tid + 256*r;
        int row = idx >> 4, qq = idx & 15;
        uint4 v = *(const uint4*)(Wb + (size_t)(nb+row)*IN_F + qq*8);
        *(uint4*)(&Bsl[row][qq*8]) = v;
    }
    __syncthreads();

    f4v acc[4][4];
    #pragma unroll
    for (int a = 0; a < 4; ++a)
        #pragma unroll
        for (int b = 0; b < 4; ++b) acc[a][b] = (f4v)0.f;

    int gmBase = mb + wm*64;
    #pragma unroll
    for (int ks = 0; ks < 4; ++ks) {
        int ko = ks*32 + q*8;
        s8v af[4], bf[4];
        #pragma unroll
        for (int mt = 0; mt < 4; ++mt) {
            int gm = gmBase + mt*16 + cl;
            uint4 va = make_uint4(0,0,0,0);
            if (gm < M) va = *(const uint4*)(Ab + (size_t)gm*IN_F + ko);
            af[mt] = *(s8v*)&va;
        }
        #pragma unroll
        for (int nt = 0; nt < 4; ++nt)
            bf[nt] = *(const s8v*)(&Bsl[wn*64 + nt*16 + cl][ko]);
        #pragma unroll
        for (int mt = 0; mt < 4; ++mt)
            #pragma unroll
            for (int nt = 0; nt < 4; ++nt)
                acc[mt][nt] = __builtin_amdgcn_mfma_f32_16x16x32_bf16(af[mt], bf[nt], acc[mt][nt], 0, 0, 0);
    }

    __syncthreads();   // all waves done reading Bsl -> reuse as C staging

    #pragma unroll
    for (int nt = 0; nt < 4; ++nt) {
        int cn = wn*64 + nt*16 + cl;
        float bv = bcat[nb + cn];
        #pragma unroll
        for (int mt = 0; mt < 4; ++mt) {
            int rm0 = wm*64 + mt*16 + q*4;
            #pragma unroll
            for (int r = 0; r < 4; ++r)
                Bsl[rm0 + r][cn] = f2bfu(acc[mt][nt][r] + bv);
        }
    }
    __syncthreads();

    #pragma unroll
    for (int p = 0; p < 8; ++p) {
        int idx = tid + 256*p;
        int row = idx >> 4, sg = idx & 15;
        int gm = mb + row;
        if (gm < M) {
            uint4 v = *(const uint4*)(&Bsl[row][sg*8]);
            *(uint4*)(Pb + (size_t)gm*PCOLS + nb + sg*8) = v;
        }
    }

    // fused Y8 emit: cols 0..95 of this tile -> fp8 rows (nb==0 blocks only)
    if (nb == 0) {
        #pragma unroll
        for (int p = 0; p < 12; ++p) {
            int idx = tid + 256*p;           // 0..3071 = 128 rows x 24 uints
            int row = idx / 24, c4 = idx - row*24;
            int gm = mb + row;
            if (gm < M) {
                uint2 v = *(const uint2*)(&Bsl[row][c4*4]);   // 4 bf16
                uintT o = ff8(bflo(v.x)) | (ff8(bfhi(v.x)) << 8)
                        | (ff8(bflo(v.y)) << 16) | (ff8(bfhi(v.y)) << 24);
                *(uintT*)(Y8 + (size_t)gm*96 + 4*c4) = o;
            }
        }
    }
}

// ===== gather core (fp8 source): 16-deep windows; rows 96 B, 2B/lane loads =====
// sv holds PRE-SCALED byte offsets (row*96). Lane loads ushort (2 fp8 feats) at
// row + 2*pL; packed HW decode (1 v_cvt_pk_f32_fp8 per 2 feats).
#define GATHER96F8(X8, lo, deg, sv, pL, sx, sy)                                   \
    float sx, sy;                                                                 \
    {                                                                             \
        f2v c0={0.f,0.f}, c1={0.f,0.f}, c2={0.f,0.f}, c3={0.f,0.f};               \
        int dmax = deg < 64 ? deg : 64;                                           \
        _Pragma("unroll 1")                                                       \
        for (int w_ = 0; w_ < dmax; w_ += 16) {                                   \
            uintT u[16];                                                          \
            _Pragma("unroll")                                                     \
            for (int kk = 0; kk < 16; ++kk) {                                     \
                int off = __builtin_amdgcn_readlane(sv, w_ + kk);                 \
                u[kk] = *(const ushortT*)((const u8T*)(X8) + off + 2*pL);         \
            }                                                                     \
            _Pragma("unroll")                                                     \
            for (int kk = 0; kk < 16; ++kk) {                                     \
                f2v v_ = CVTPK(u[kk], 0);                                         \
                switch (kk & 3) {                                                 \
                    case 0: c0 += v_; break;                                      \
                    case 1: c1 += v_; break;                                      \
                    case 2: c2 += v_; break;                                      \
                    default:c3 += v_; break;                                      \
                }                                                                 \
            }                                                                     \
        }                                                                         \
        if (deg > 64) {                                                           \
            _Pragma("unroll 1")                                                   \
            for (int j_ = lo + 64; j_ < lo + deg; ++j_) {                         \
                int off = src[j_] * 96;                                           \
                uintT u0 = *(const ushortT*)((const u8T*)(X8) + off + 2*pL);      \
                c0 += CVTPK(u0, 0);                                               \
            }                                                                     \
        }                                                                         \
        f2v cs_ = (c0 + c1) + (c2 + c3);                                          \
        sx = cs_.x; sy = cs_.y;                                                   \
    }

// per-lane gather slot from raw src: lane<deg ? src[lo+lane]*96 : dummy row N
// (kept PER-ITERATION — r9/r10 proved upfront batching regresses)
#define MAKE_SV96(lo, deg, lane, sv)                                              \
    int sv;                                                                       \
    {                                                                             \
        int e_ = (lo) + (lane);                                                   \
        if (e_ > E_EDGES - 1) e_ = E_EDGES - 1;                                   \
        int sn_ = src[e_];                                                        \
        sv = ((lane) < (deg) ? sn_ : N_NODES) * 96;                               \
    }

// ---------- layer 1: rb1 = bf16(relu(Lap(Y0) + Zpre)); gather from fp8 Y8 ----------
__global__ __launch_bounds__(256) void lap1(
    const ushortT* __restrict__ Pb,    // own-x (cols 0..95) + Zpre (96..191), bf16
    const u8T*     __restrict__ Y8,    // fp8 gather source [N+1,96]
    const int* __restrict__ src, const int* __restrict__ row_ptr,
    ushortT* __restrict__ rb1, u8T* __restrict__ rb1f8)
{
    int lane = threadIdx.x & 63;
    int t  = __builtin_amdgcn_readfirstlane((blockIdx.x << 2) + (threadIdx.x >> 6));
    int lo = __builtin_amdgcn_readfirstlane(row_ptr[t]);
    int deg = __builtin_amdgcn_readfirstlane(row_ptr[t+1]) - lo;
    int pL = lane < 48 ? lane : 0;
    MAKE_SV96(lo, deg, lane, sv)
    uintT ux = *(const uintT*)(Pb + (size_t)t*PCOLS + 2*pL);        // Y0 bf16
    uintT zu = *(const uintT*)(Pb + (size_t)t*PCOLS + 96 + 2*pL);   // Zpre

    GATHER96F8(Y8, lo, deg, sv, pL, sx, sy)

    float inv = deg > 0 ? 1.f/(float)deg : 0.f;
    float mf  = deg > 0 ? 1.f : 0.f;
    if (lane < 48) {
        float ox = fmaxf(mf*bflo(ux) - sx*inv + bflo(zu), 0.f);
        float oy = fmaxf(mf*bfhi(ux) - sy*inv + bfhi(zu), 0.f);
        *(uintT*)(rb1 + (size_t)t*96 + 2*pL) = pack2(ox, oy);
        *(ushortT*)(rb1f8 + (size_t)t*96 + 2*pL) = (ushortT)(ff8(ox) | (ff8(oy) << 8));
    }
}

// ---------- layer 2: rb2 = bf16(relu(Lap(rb1)@W_blk + Zblk)); gather fp8 ----------
__global__ __launch_bounds__(256) void lap2(
    const ushortT* __restrict__ Xb,    // rb1 bf16 (own-x)
    const u8T*     __restrict__ X8,    // rb1 fp8 (gather)
    const ushortT* __restrict__ Pb,    // Zblk = cols 192..287
    const int* __restrict__ src, const int* __restrict__ row_ptr,
    const float* __restrict__ Wblk,    // [3][32][32] flat
    ushortT* __restrict__ rb2, u8T* __restrict__ rb2f8)
{
    __shared__ float wS[3*32*32];
    for (int i = threadIdx.x; i < 3072; i += 256) wS[i] = Wblk[i];
    __syncthreads();

    int lane = threadIdx.x & 63;
    int wvw  = threadIdx.x >> 6;
    int pL = lane < 48 ? lane : 0;
    int w  = pL >> 4;            // group (uniform per 16-lane slab)
    int jj = pL & 15;            // out pair index within group
    const float2* wc = ((const float2*)wS) + (w*512 + jj);   // &W[w][0][2jj]

    #pragma unroll 1
    for (int it = 0; it < 4; ++it) {
        int t  = __builtin_amdgcn_readfirstlane(blockIdx.x*16 + it*4 + wvw);
        int lo = __builtin_amdgcn_readfirstlane(row_ptr[t]);
        int deg = __builtin_amdgcn_readfirstlane(row_ptr[t+1]) - lo;
        MAKE_SV96(lo, deg, lane, sv)
        uintT ux = *(const uintT*)(Xb + (size_t)t*96 + 2*pL);
        uintT zu = *(const uintT*)(Pb + (size_t)t*PCOLS + 192 + 2*pL);

        GATHER96F8(X8, lo, deg, sv, pL, sx, sy)

        float inv = deg > 0 ? 1.f/(float)deg : 0.f;
        float mf  = deg > 0 ? 1.f : 0.f;
        float Lx = mf*bflo(ux) - sx*inv;    // Lap feat 2pL
        float Ly = mf*bfhi(ux) - sy*inv;    // Lap feat 2pL+1

        // conv (no bias): out channels (2pL, 2pL+1), inputs = group-w feats via shfl
        float accx = 0.f, accy = 0.f;
        #pragma unroll
        for (int d = 0; d < 16; ++d) {
            int sl = w*16 + d;
            float ax = __shfl(Lx, sl);      // feat 32w+2d
            float ay = __shfl(Ly, sl);      // feat 32w+2d+1
            float2 wa = wc[(2*d)*16];       // W[w][2d][2jj..2jj+1]
            float2 wb = wc[(2*d+1)*16];
            accx = fmaf(ax, wa.x, accx); accx = fmaf(ay, wb.x, accx);
            accy = fmaf(ax, wa.y, accy); accy = fmaf(ay, wb.y, accy);
        }
        if (lane < 48) {
            float ox = fmaxf(accx + bflo(zu), 0.f);
            float oy = fmaxf(accy + bfhi(zu), 0.f);
            *(uintT*)(rb2 + (size_t)t*96 + 2*pL) = pack2(ox, oy);
            *(ushortT*)(rb2f8 + (size_t)t*96 + 2*pL) = (ushortT)(ff8(ox) | (ff8(oy) << 8));
        }
    }
}

// ---------- layer 3: out = widthmean(relu(Lap(rb2)@W_post + Zpost)); gather fp8 ----------
__global__ __launch_bounds__(256) void lap3(
    const ushortT* __restrict__ Xb,    // rb2 bf16 (own-x)
    const u8T*     __restrict__ X8,    // rb2 fp8 (gather)
    const ushortT* __restrict__ Pb,    // Zpost = cols 288..479
    const int* __restrict__ src, const int* __restrict__ row_ptr,
    const float2* __restrict__ Wp2,    // [3][16][64] float2
    float* __restrict__ out)
{
    __shared__ float2 wS[3*16*64];
    __shared__ float  sm[4][96];       // per-wave activation slab (wave DS in-order)
    for (int i = threadIdx.x; i < 3072; i += 256) wS[i] = Wp2[i];
    __syncthreads();

    int lane = threadIdx.x & 63;
    int wvw  = threadIdx.x >> 6;
    int pL = lane < 48 ? lane : 0;
    const float2* wl = wS + lane;      // step 64 float2 per (w,i2)

    #pragma unroll 1
    for (int it = 0; it < 4; ++it) {
        int t  = __builtin_amdgcn_readfirstlane(blockIdx.x*16 + it*4 + wvw);
        int lo = __builtin_amdgcn_readfirstlane(row_ptr[t]);
        int deg = __builtin_amdgcn_readfirstlane(row_ptr[t+1]) - lo;
        MAKE_SV96(lo, deg, lane, sv)
        uintT ux = *(const uintT*)(Xb + (size_t)t*96 + 2*pL);
        float z0 = bflo((uintT)Pb[(size_t)t*PCOLS + 288 + lane]);   // ch lane
        float z1 = bflo((uintT)Pb[(size_t)t*PCOLS + 352 + lane]);   // ch 64+lane
        float z2 = bflo((uintT)Pb[(size_t)t*PCOLS + 416 + lane]);   // ch 128+lane

        GATHER96F8(X8, lo, deg, sv, pL, sx, sy)

        float inv = deg > 0 ? 1.f/(float)deg : 0.f;
        float mf  = deg > 0 ? 1.f : 0.f;
        float Lx = mf*bflo(ux) - sx*inv;
        float Ly = mf*bfhi(ux) - sy*inv;

        // broadcast activations through per-wave LDS (uniform-address ds_read = broadcast)
        if (lane < 48) {
            sm[wvw][2*pL]     = Lx;
            sm[wvw][2*pL + 1] = Ly;
        }
        __builtin_amdgcn_wave_barrier();   // pin compiler order; wave DS ops are HW-in-order

        // conv: lane computes channels {L, 64+L, 128+L}
        float a0 = 0.f, a1 = 0.f, a2 = 0.f;
        #pragma unroll
        for (int w2 = 0; w2 < 3; ++w2) {
            float acc = 0.f;
            #pragma unroll
            for (int i2 = 0; i2 < 16; ++i2) {
                float2 iv = *(const float2*)(&sm[wvw][w2*32 + 2*i2]);   // broadcast read
                float2 p  = wl[(w2*16 + i2)*64];
                acc = fmaf(iv.x, p.x, acc);
                acc = fmaf(iv.y, p.y, acc);
            }
            if (w2 == 0) a0 = acc; else if (w2 == 1) a1 = acc; else a2 = acc;
        }
        __builtin_amdgcn_wave_barrier();   // reads done before next iter's sm writes

        float o0 = fmaxf(a0 + z0, 0.f);   // channel lane
        float o1 = fmaxf(a1 + z1, 0.f);   // channel 64+lane
        float o2 = fmaxf(a2 + z2, 0.f);   // channel 128+lane
        // width-mean: final[f] = (v(3f)+v(3f+1)+v(3f+2))/3, v(c) = o_{c>>6} @ lane c&63
        float r = 0.f;
        #pragma unroll
        for (int q = 0; q < 3; ++q) {
            int c = 3*lane + q;
            int sl = c & 63, wsel = c >> 6;
            float v0 = __shfl(o0, sl);
            float v1 = __shfl(o1, sl);
            float v2 = __shfl(o2, sl);
            r += (wsel == 0) ? v0 : ((wsel == 1) ? v1 : v2);
        }
        out[(size_t)t*64 + lane] = r * (1.0f/3.0f);
    }
}

extern "C" void kernel_launch(void* const* d_in, const int* in_sizes, int n_in,
                              void* d_out, int out_size, void* d_ws, size_t ws_size,
                              hipStream_t stream)
{
    const float* data    = (const float*)d_in[0];
    const int*   src     = (const int*)  d_in[1];
    const int*   tgt     = (const int*)  d_in[2];
    const float* W_pre   = (const float*)d_in[3];
    const float* b_pre   = (const float*)d_in[4];
    const float* T_pre   = (const float*)d_in[5];
    const float* bT_pre  = (const float*)d_in[6];
    const float* W_blk   = (const float*)d_in[7];
    const float* b_blk   = (const float*)d_in[8];   // cancels under Lap — unused
    const float* T_blk   = (const float*)d_in[9];
    const float* bT_blk  = (const float*)d_in[10];
    const float* W_post  = (const float*)d_in[11];
    const float* b_post  = (const float*)d_in[12];  // cancels under Lap — unused
    const float* T_post  = (const float*)d_in[13];
    const float* bT_post = (const float*)d_in[14];
    float* out = (float*)d_out;

    float*   ws      = (float*)d_ws;
    float*   bcat    = ws;                                   // 512 f32
    float2*  Wp2     = (float2*)(bcat + 512);                // 3*16*64 float2
    int*     row_ptr = (int*)(Wp2 + 3*16*64);                // 50008
    ushortT* Pb      = (ushortT*)(row_ptr + 50008);          // (N+1)*512 bf16
    ushortT* rb1     = Pb  + (size_t)(N_NODES+1) * PCOLS;    // (N+1)*96 bf16
    ushortT* rb2     = rb1 + (size_t)(N_NODES+1) * 96;       // (N+1)*96 bf16
    ushortT* Ab      = rb2 + (size_t)(N_NODES+1) * 96;       // N*128 bf16
    ushortT* Wb      = Ab  + (size_t)N_NODES * IN_F;         // 512*128 bf16
    u8T*     Y8      = (u8T*)(Wb + 512*IN_F);                // (N+1)*96 fp8
    u8T*     rb1f8   = Y8  + (size_t)(N_NODES+1) * 96;       // (N+1)*96 fp8
    u8T*     rb2f8   = rb1f8 + (size_t)(N_NODES+1) * 96;     // (N+1)*96 fp8

    prep1<<<(N_NODES*IN_F/8)/256, 256, 0, stream>>>(
        data, W_pre, b_pre, T_pre, bT_pre, T_blk, bT_blk, T_post, bT_post,
        W_post, tgt, Wb, bcat, Wp2, Ab, row_ptr, Y8, rb1f8, rb2f8);

    gemm_mfma<<<1568, 256, 0, stream>>>(Ab, Wb, bcat, Pb, Y8, N_NODES);

    lap1<<<N_NODES/4, 256, 0, stream>>>(Pb, Y8, src, row_ptr, rb1, rb1f8);
    lap2<<<N_NODES/16, 256, 0, stream>>>(rb1, rb1f8, Pb, src, row_ptr, W_blk, rb2, rb2f8);
    lap3<<<N_NODES/16, 256, 0, stream>>>(rb2, rb2f8, Pb, src, row_ptr, Wp2, out);
}